// Round 7
// baseline (2230.420 us; speedup 1.0000x reference)
//
#include <hip/hip_runtime.h>
#include <hip/hip_bf16.h>

// BeamDecoder: greedy CVRP-style decode.
// s_i(step) = c*( G[last,i] + (load/cap)*u_i )   (v==0 since bq==0; folded)
//
// R16: R15's endgame + dwin-ballot regressed (1392 vs R13 1308) -> reverted.
// R13's cert path = ~780cyc, dominated by TWO chained LDS latencies:
// s_pc[row] read -> i1x -> dependent s_du[i1x] gather. Fix: fuse everything
// into one 8-byte LDS entry per candidate -> tier-1 is ONE ds_read_b64:
//   entry u64 = [g_key21 | idx11 | u_bf16(RNE) | d_bf16(round-UP)]
// (u ~ N(0,1), d in (0,1): bf16 err <= 0.0156 for |u|<8; flag otherwise).
// Feasibility via certified bounds: d <= dh (stored round-up), d > dl =
// pred(dh). possible = dl < load (superset of feasible); winner must be
// DEFINITE (dh <= load) else fallback. Visited tracking (was s_du's INF)
// moves to a per-lane 32-bit register bitmask; winner-visited checked by a
// cheap post-reduce ballot -> fallback (sound, conservative late).
// Error budget: 2*(eps_g 0.0156 + eps_u 0.0156) + t-key trunc 0.125 (|t| <
// 136 < 256 guaranteed by flags |g|>=128 / |u|>=8) -> EGM = 0.25, MARGIN =
// 0.5 (typical top-2 gap ~9 at sigma_g=32 -> cert-rate cost ~2%).
// KL=8 (LDS: 128K pc8 + 16K du + 8K thr8 + 4.6K tour = 160.3KB). Tier-2
// thresholds move to global (read inside fallback branch only). Tier-2 =
// R13-verbatim exact 128-list on demand; tier-3 = R5-verbatim scan.
// Cert chain ~300-340cyc vs R13's ~780. Scores exact via deferred pass.

#define NN 2048
#define HH 1024
#define TSTEPS (NN + NN / 8)   // 2304
#define TILE 64
#define KT 16
#define KCAND 128
#define KL8 8

// ---------------- pack Wq[:, :H] into ld=1024 buffer ----------------
__global__ __launch_bounds__(256) void prep_wqh(const float* __restrict__ Wq,
                                                float* __restrict__ Wqh) {
  int id = blockIdx.x * 256 + threadIdx.x;
  int r = id >> 10, c = id & 1023;
  Wqh[id] = Wq[r * (HH + 2) + c];
}

// ---------------- NT GEMM: C[M,N] = A[M,K] @ B[N,K]^T (+ bias[n]) ----------------
__global__ __launch_bounds__(256) void gemm_nt(const float* __restrict__ A, int lda,
                                               const float* __restrict__ B, int ldb,
                                               float* __restrict__ C, int ldc,
                                               int K, const float* __restrict__ bias) {
  __shared__ float As[KT][TILE + 4];
  __shared__ float Bs[KT][TILE + 4];
  const int i0 = blockIdx.y * TILE;
  const int j0 = blockIdx.x * TILE;
  const int t = threadIdx.x;
  const int srow = t >> 2, sq = t & 3;
  const int tx = t & 15, ty = t >> 4;
  float acc[4][4] = {};
  for (int k0 = 0; k0 < K; k0 += KT) {
    float4 av = *(const float4*)&A[(size_t)(i0 + srow) * lda + k0 + sq * 4];
    float4 bv = *(const float4*)&B[(size_t)(j0 + srow) * ldb + k0 + sq * 4];
    __syncthreads();
    As[sq * 4 + 0][srow] = av.x; As[sq * 4 + 1][srow] = av.y;
    As[sq * 4 + 2][srow] = av.z; As[sq * 4 + 3][srow] = av.w;
    Bs[sq * 4 + 0][srow] = bv.x; Bs[sq * 4 + 1][srow] = bv.y;
    Bs[sq * 4 + 2][srow] = bv.z; Bs[sq * 4 + 3][srow] = bv.w;
    __syncthreads();
#pragma unroll
    for (int k = 0; k < KT; ++k) {
      float4 a4 = *(const float4*)&As[k][ty * 4];
      float4 b4 = *(const float4*)&Bs[k][tx * 4];
      float a[4] = {a4.x, a4.y, a4.z, a4.w};
      float b[4] = {b4.x, b4.y, b4.z, b4.w};
#pragma unroll
      for (int m = 0; m < 4; ++m)
#pragma unroll
        for (int n = 0; n < 4; ++n) acc[m][n] = fmaf(a[m], b[n], acc[m][n]);
    }
  }
  float bb[4] = {0.f, 0.f, 0.f, 0.f};
  if (bias) {
#pragma unroll
    for (int n = 0; n < 4; ++n) bb[n] = bias[j0 + tx * 4 + n];
  }
#pragma unroll
  for (int m = 0; m < 4; ++m) {
    float4 st = {acc[m][0] + bb[0], acc[m][1] + bb[1], acc[m][2] + bb[2], acc[m][3] + bb[3]};
    *(float4*)&C[(size_t)(i0 + ty * 4 + m) * ldc + j0 + tx * 4] = st;
  }
}

// ---------------- u_i = K_i . Wq[:,H], v_i = K_i . bq  (one wave per row) ---------
__global__ __launch_bounds__(64) void uv_k(const float* __restrict__ Kmat,
                                           const float* __restrict__ Wq,
                                           const float* __restrict__ bq,
                                           float* __restrict__ u, float* __restrict__ v) {
  int i = blockIdx.x;
  int lane = threadIdx.x;
  float su = 0.f, sv = 0.f;
#pragma unroll
  for (int m = 0; m < HH / 64; ++m) {
    int j = lane + 64 * m;
    float kv = Kmat[(size_t)i * HH + j];
    su = fmaf(kv, Wq[(size_t)j * (HH + 2) + HH], su);
    sv = fmaf(kv, bq[j], sv);
  }
#pragma unroll
  for (int off = 32; off; off >>= 1) {
    su += __shfl_down(su, off, 64);
    sv += __shfl_down(sv, off, 64);
  }
  if (lane == 0) { u[i] = su; v[i] = sv; }
}

// ---------------- helpers ----------------
__device__ __forceinline__ unsigned f2key(float f) {
  unsigned x = __float_as_uint(f);
  return x ^ ((x >> 31) ? 0xFFFFFFFFu : 0x80000000u);  // monotonic asc mapping
}
__device__ __forceinline__ float key2f(unsigned k) {
  unsigned x = (k & 0x80000000u) ? (k ^ 0x80000000u) : ~k;
  return __uint_as_float(x);
}
// bf16-style round-UP (toward +inf). ub16f(x) >= x always (x > 0 or inf).
__device__ __forceinline__ unsigned ub16(float x) {
  unsigned b = __float_as_uint(x);
  if (x > 0.f && (b & 0xFFFFu)) b += 0x10000u;
  return b >> 16;
}
// bf16 round-to-nearest-even.
__device__ __forceinline__ unsigned bf16rne(float x) {
  unsigned b = __float_as_uint(x);
  b += 0x7FFFu + ((b >> 16) & 1u);
  return b >> 16;
}

// Produces: cand[row][0..127] exact top-128 (value,idx);
// pc8[row][0..7] fused entries uint2{.x = u_bf16<<16 | d_up_bf16,
//                                    .y = g_key21 | idx11};
// thr8g[row] = ub16(thr8)<<16 | ub16(M1_8)     (+inf halves when flagged)
// thr2g[row] = ub16(thr128)<<16 | ub16(M1_128)
// M1_K = max over j NOT in the stored top-K list of (g_j + u_j).
// Flag: any stored top-8 entry with |g| >= 128 or |u| >= 8 (bounds the
// 21-bit g error, bf16 u error, and decode t-key truncation: |t| < 136).
__global__ __launch_bounds__(256) void prep_cand(const float* __restrict__ GT,
                                                 const float* __restrict__ u,
                                                 const float* __restrict__ demands,
                                                 uint2* __restrict__ cand,
                                                 uint2* __restrict__ pc8,
                                                 unsigned* __restrict__ thr8g,
                                                 unsigned* __restrict__ thr2g) {
  __shared__ float rowv[NN];
  __shared__ float su_[NN];
  __shared__ int hist[256];
  __shared__ float red8[256];
  __shared__ float red128[256];
  __shared__ unsigned c128k[KCAND];
  __shared__ int c128i[KCAND];
  __shared__ unsigned char markA[NN];  // in stored top-128
  __shared__ unsigned char markB[NN];  // in stored top-8
  __shared__ int s_d, s_need, s_gt, s_eq, s_gt2, s_eq2, s_flag;
  const int row = blockIdx.x, t = threadIdx.x;
  for (int i = t; i < NN; i += 256) {
    rowv[i] = GT[(size_t)row * NN + i];
    su_[i] = u[i];
    markA[i] = 0;
    markB[i] = 0;
  }
  __syncthreads();
  unsigned prefix = 0;
  int need = KCAND;
  for (int pass = 0; pass < 4; ++pass) {
    hist[t] = 0;
    __syncthreads();
    const int shift = 24 - 8 * pass;
    for (int i = t; i < NN; i += 256) {
      unsigned k = f2key(rowv[i]);
      if (pass == 0 || (k >> (shift + 8)) == (prefix >> (shift + 8)))
        atomicAdd(&hist[(k >> shift) & 0xFF], 1);
    }
    __syncthreads();
    if (t == 0) {
      int cum = 0, d = 255;
      for (; d > 0; --d) {
        if (cum + hist[d] >= need) break;
        cum += hist[d];
      }
      s_d = d;
      s_need = need - cum;
    }
    __syncthreads();
    prefix |= ((unsigned)s_d) << shift;
    need = s_need;
    __syncthreads();
  }
  const unsigned thrk = prefix;  // exact KCAND-th largest key
  if (t == 0) { s_gt = 0; s_eq = 0; }
  __syncthreads();
  for (int i = t; i < NN; i += 256) {
    unsigned k = f2key(rowv[i]);
    if (k > thrk) {
      int p = atomicAdd(&s_gt, 1);
      cand[(size_t)row * KCAND + p] = make_uint2(__float_as_uint(rowv[i]), (unsigned)i);
      c128k[p] = k;
      c128i[p] = i;
      markA[i] = 1;
    }
  }
  __syncthreads();
  const int cgt = s_gt;
  for (int i = t; i < NN; i += 256) {
    if (f2key(rowv[i]) == thrk) {
      int p = atomicAdd(&s_eq, 1);
      if (p < KCAND - cgt) {
        cand[(size_t)row * KCAND + cgt + p] = make_uint2(__float_as_uint(rowv[i]), (unsigned)i);
        c128k[cgt + p] = thrk;
        c128i[cgt + p] = i;
        markA[i] = 1;
      }
    }
  }
  __syncthreads();
  // ---- exact 8th-largest among the 128 keys (== row's top-8 multiset)
  unsigned pfx2 = 0;
  need = KL8;
  for (int pass = 0; pass < 4; ++pass) {
    hist[t] = 0;
    __syncthreads();
    const int shift = 24 - 8 * pass;
    for (int i = t; i < KCAND; i += 256) {
      unsigned k = c128k[i];
      if (pass == 0 || (k >> (shift + 8)) == (pfx2 >> (shift + 8)))
        atomicAdd(&hist[(k >> shift) & 0xFF], 1);
    }
    __syncthreads();
    if (t == 0) {
      int cum = 0, d = 255;
      for (; d > 0; --d) {
        if (cum + hist[d] >= need) break;
        cum += hist[d];
      }
      s_d = d;
      s_need = need - cum;
    }
    __syncthreads();
    pfx2 |= ((unsigned)s_d) << shift;
    need = s_need;
    __syncthreads();
  }
  const unsigned thrk8 = pfx2;
  if (t == 0) { s_gt2 = 0; s_eq2 = 0; s_flag = 0; }
  __syncthreads();
  for (int i = t; i < KCAND; i += 256) {
    if (c128k[i] > thrk8) {
      int p = atomicAdd(&s_gt2, 1);
      int idx = c128i[i];
      float uu = su_[idx];
      float dd = demands[idx];
      pc8[(size_t)row * KL8 + p] =
          make_uint2((bf16rne(uu) << 16) | ub16(dd),
                     (c128k[i] & 0xFFFFF800u) | (unsigned)idx);
      markB[idx] = 1;
      if (fabsf(key2f(c128k[i])) >= 128.0f || fabsf(uu) >= 8.0f) s_flag = 1;
    }
  }
  __syncthreads();
  const int cgt2 = s_gt2;
  for (int i = t; i < KCAND; i += 256) {
    if (c128k[i] == thrk8) {
      int p = atomicAdd(&s_eq2, 1);
      if (p < KL8 - cgt2) {
        int idx = c128i[i];
        float uu = su_[idx];
        float dd = demands[idx];
        pc8[(size_t)row * KL8 + cgt2 + p] =
            make_uint2((bf16rne(uu) << 16) | ub16(dd),
                       (thrk8 & 0xFFFFF800u) | (unsigned)idx);
        markB[idx] = 1;
        if (fabsf(key2f(thrk8)) >= 128.0f || fabsf(uu) >= 8.0f) s_flag = 1;
      }
    }
  }
  __syncthreads();
  // ---- M1_8 / M1_128: max of (g + u) over nodes outside each stored list
  float lm8 = -__builtin_inff(), lm128 = -__builtin_inff();
  for (int i = t; i < NN; i += 256) {
    float gu = rowv[i] + su_[i];
    if (!markB[i]) lm8 = fmaxf(lm8, gu);
    if (!markA[i]) lm128 = fmaxf(lm128, gu);
  }
  red8[t] = lm8;
  red128[t] = lm128;
  __syncthreads();
  for (int s = 128; s; s >>= 1) {
    if (t < s) {
      red8[t] = fmaxf(red8[t], red8[t + s]);
      red128[t] = fmaxf(red128[t], red128[t + s]);
    }
    __syncthreads();
  }
  if (t == 0) {
    const float INF = __builtin_inff();
    float t8 = s_flag ? INF : key2f(thrk8);
    float m8 = s_flag ? INF : red8[0];
    thr8g[row] = (ub16(t8) << 16) | ub16(m8);
    thr2g[row] = (ub16(key2f(thrk)) << 16) | ub16(red128[0]);
  }
}

// ---------------- LLC pre-warm for the tier-2 fallback lists ---------------------
__global__ __launch_bounds__(256) void warm_k(const float* __restrict__ a, int n,
                                              float* __restrict__ sink) {
  float s = 0.f;
  const float4* a4 = (const float4*)a;
  for (int i = threadIdx.x; i < n / 4; i += 256) {
    float4 x = a4[i];
    s += x.x + x.y + x.z + x.w;
  }
  if (s == 1.2345e-30f) sink[blockIdx.x] = s;  // never true; keeps loads alive
}

// DPP merge of (bv,bi): max value, smallest index on ties. Invalid lanes get
// (-inf, INT_MAX).
#define DPP_MERGE2(CTRL)                                                      \
  {                                                                           \
    int ovb = __builtin_amdgcn_update_dpp(                                    \
        (int)0xFF800000, __float_as_int(bv), (CTRL), 0xf, 0xf, false);        \
    int oib = __builtin_amdgcn_update_dpp(                                    \
        0x7fffffff, bi, (CTRL), 0xf, 0xf, false);                             \
    float ov = __int_as_float(ovb);                                           \
    if (ov > bv || (ov == bv && oib < bi)) { bv = ov; bi = oib; }             \
  }

// Packed u32 max + runner-up over lanes 0..7 (row_shr within 16-lane row).
// key 0 = invalid sentinel (< any real candidate key).
#define KRED(CTRL)                                                            \
  {                                                                           \
    unsigned o1 = (unsigned)__builtin_amdgcn_update_dpp(                      \
        0, (int)m1, (CTRL), 0xf, 0xf, false);                                 \
    unsigned o2 = (unsigned)__builtin_amdgcn_update_dpp(                      \
        0, (int)m2, (CTRL), 0xf, 0xf, false);                                 \
    unsigned mn = min(m1, o1);                                                \
    m1 = max(m1, o1);                                                         \
    m2 = max(max(m2, o2), mn);                                                \
  }

struct Pick { int take; int nxt; };

// Tier-3: R5-verbatim exact full-row scan. Cold; kept out of the hot loop's
// instruction stream.
__device__ __noinline__ Pick tier3_scan(const float* __restrict__ GT,
                                        const float2* sdu, int row, int lane,
                                        float load, float lr, int depot) {
  const float NEGINF = -__builtin_inff();
  const float4* rowp = (const float4*)(GT + (size_t)row * NN);
  const float4* du4 = (const float4*)sdu;
  float fv = NEGINF;
  int fi = NN;
#pragma unroll
  for (int r = 0; r < 8; ++r) {
    float4 g4 = rowp[r * 64 + lane];
    float4 pA = du4[(r * 64 + lane) * 2];      // d0,u0,d1,u1
    float4 pB = du4[(r * 64 + lane) * 2 + 1];  // d2,u2,d3,u3
    float gl[4] = {g4.x, g4.y, g4.z, g4.w};
    float dl[4] = {pA.x, pA.z, pB.x, pB.z};
    float ul[4] = {pA.y, pA.w, pB.y, pB.w};
    float cv = NEGINF;
    int cj = 0;
#pragma unroll
    for (int j = 0; j < 4; ++j) {
      float tt = fmaf(ul[j], lr, gl[j]);
      bool feas = (dl[j] <= load);
      if (feas && tt > cv) { cv = tt; cj = j; }
    }
    if (cv > fv) { fv = cv; fi = 4 * (r * 64 + lane) + cj; }  // asc r: first-max
  }
  float bv = fv;
  int bi = fi;
  DPP_MERGE2(0x111); DPP_MERGE2(0x112); DPP_MERGE2(0x114);
  DPP_MERGE2(0x118); DPP_MERGE2(0x142); DPP_MERGE2(0x143);
  float fbv = __int_as_float(__builtin_amdgcn_readlane(__float_as_int(bv), 63));
  int fbi = __builtin_amdgcn_readlane(bi, 63);
  Pick p;
  p.take = (fbv > NEGINF) ? 1 : 0;
  p.nxt = p.take ? fbi : depot;
  return p;
}

// ---------------- sequential decode: ONE wave ------------------------------------
// Tier-1: ONE ds_read_b64 fused entry, register visited-mask, no dependent
// gather. Tier-2/3 on demand (thresholds for tier-2 read from global inside
// the fallback branch only).
__global__ __launch_bounds__(64, 1) void decode(const float* __restrict__ GT,
                                                const uint2* __restrict__ cand,
                                                const uint2* __restrict__ pc8,
                                                const unsigned* __restrict__ thr8g,
                                                const unsigned* __restrict__ thr2g,
                                                const float* __restrict__ u,
                                                const float* __restrict__ demands,
                                                const int* __restrict__ capp,
                                                const int* __restrict__ depotp,
                                                float* __restrict__ lrbuf,
                                                float* __restrict__ out) {
  __shared__ __align__(16) uint2 s_pc8[NN * KL8];         // 128 KB fused lists
  __shared__ __align__(16) float2 s_du[NN];               // 16 KB (.x=d|+inf, .y=u)
  __shared__ __align__(16) unsigned s_thr[NN];            // 8 KB ub16(thr8)|ub16(M1_8)
  __shared__ __align__(16) unsigned short s_tour[TSTEPS + 2];  // 4.6 KB

  const int lane = threadIdx.x;
  const int depot = *depotp;
  const float capf = (float)(*capp);
  const float INF = __builtin_inff();
  const float C0 = 0.015625f;   // ALPHA / sqrt(HID), exact power of two
  const float MARGIN = 0.5f;    // >> all bound-side rounding
  const float EGM = 0.25f;      // > 2*(eps_g+eps_u)=0.0625 + t-key trunc 0.125
  float* sduf = (float*)s_du;

  for (int i = lane; i < NN; i += 64) {
    s_du[i] = make_float2(demands[i], u[i]);
    s_thr[i] = thr8g[i];
  }
  {
    const uint4* p4 = (const uint4*)pc8;
    uint4* q4 = (uint4*)s_pc8;
    for (int i = lane; i < NN * KL8 / 2; i += 64) q4[i] = p4[i];
  }
  if (lane == 0) {
    sduf[2 * depot] = INF;  // depot starts visited (tier-2/3 view)
    s_tour[0] = (unsigned short)depot;
  }
  // per-lane visited bitmask: bit j of lane l => node l*32+j visited
  unsigned vmask = 0u;
  if (lane == (depot >> 5)) vmask |= 1u << (depot & 31);
  // single wave: per-wave LDS ordering suffices; no barrier needed

  int ntaken = 0, lasts = depot;
  float load = capf;
  float lr = load / capf;  // same fp32 division as reference
  int step = 0;
  const int lcl8 = (lane < KL8) ? lane : (KL8 - 1);

  for (; step < TSTEPS; ++step) {
    const int row = lasts;
    // ---- tier-1: one fused ds_read_b64, no dependent gather
    uint2 e = s_pc8[(row << 3) + lcl8];
    unsigned pk = s_thr[row];
    int i1x = (int)(e.y & 0x7FFu);
    float g1 = key2f(e.y & 0xFFFFF800u);          // g_hat <= g <= g_hat+0.0156
    float u1 = __uint_as_float(e.x & 0xFFFF0000u); // |u - u1| <= 0.0156 (|u|<8)
    unsigned dhb = e.x << 16;
    float dh = __uint_as_float(dhb);               // d <= dh
    float dl = __uint_as_float(dhb - 0x00010000u); // d >  dl (pred bf16)
    float t1 = fmaf(u1, lr, g1);
    bool poss = (lane < KL8) && (dl < load);       // superset of feasible
    unsigned m1 = poss ? ((f2key(t1) & 0xFFFFF800u) | ((~(unsigned)i1x) & 0x7FFu)) : 0u;
    unsigned m2 = 0u;
    KRED(0x111); KRED(0x112); KRED(0x114);
    unsigned rv1k = (unsigned)__builtin_amdgcn_readlane((int)m1, 7);
    unsigned rv2k = (unsigned)__builtin_amdgcn_readlane((int)m2, 7);
    float rv1f = key2f(rv1k & 0xFFFFF800u);  // round-down: lower bd of winner t_hat
    float rv2f = key2f(rv2k | 0x7FFu);       // round-up: upper bd of runner-up
    int wid = (int)((~rv1k) & 0x7FFu);
    float t8 = __uint_as_float(pk & 0xFFFF0000u);
    float m8 = __uint_as_float(pk << 16);
    float B1 = fmaf(1.0f - lr, t8, lr * m8) + MARGIN;  // convex outside bound
    // winner definitely-feasible? winner unvisited? (cheap ballots, no LDS)
    unsigned long long okb = __ballot((lane < KL8) && (i1x == wid) && (dh <= load));
    unsigned long long visb = __ballot((lane == (wid >> 5)) && ((vmask >> (wid & 31)) & 1u));
    int take, nxt;
    if (__builtin_expect((rv1f > B1) && (rv1f > rv2f + EGM) &&
                         (okb != 0ull) && (visb == 0ull), 1)) {
      // certified: winner strictly beats all in-list (EGM > total err),
      // all outside-list (B1 convex bound + MARGIN), is definitely feasible
      // (d <= dh <= load) and unvisited. Unique argmax == ref's pick.
      // (rv1k==0 -> rv1f NaN -> compares false -> fallback.)
      take = 1;
      nxt = wid;
    } else {
      // ---- tier-2: on-demand exact eval of the 128-candidate list
      uint4 cc = ((const uint4*)(cand + (size_t)row * KCAND))[lane];
      unsigned pk2 = thr2g[row];  // uniform load, waited only in this branch
      float bv = -INF;
      int bi = 0x7fffffff;
      {
        float ga = __uint_as_float(cc.x); int ia = (int)cc.y;
        float gb = __uint_as_float(cc.z); int ib = (int)cc.w;
        float2 da = s_du[ia];
        float2 db = s_du[ib];
        float ta = fmaf(da.y, lr, ga);
        float tb = fmaf(db.y, lr, gb);
        if ((da.x <= load) && (ta > bv || (ta == bv && ia < bi))) { bv = ta; bi = ia; }
        if ((db.x <= load) && (tb > bv || (tb == bv && ib < bi))) { bv = tb; bi = ib; }
      }
      DPP_MERGE2(0x111); DPP_MERGE2(0x112); DPP_MERGE2(0x114);
      DPP_MERGE2(0x118); DPP_MERGE2(0x142); DPP_MERGE2(0x143);
      float rbv = __int_as_float(__builtin_amdgcn_readlane(__float_as_int(bv), 63));
      int rbi = __builtin_amdgcn_readlane(bi, 63);
      float t128 = __uint_as_float(pk2 & 0xFFFF0000u);
      float m128 = __uint_as_float(pk2 << 16);
      float B2 = fmaf(1.0f - lr, t128, lr * m128) + MARGIN;
      if (rbv > B2) {
        take = 1; nxt = rbi;
      } else {
        Pick p = tier3_scan(GT, (const float2*)s_du, row, lane, load, lr, depot);
        take = p.take; nxt = p.nxt;
      }
    }

    // ---- state update + output stores (identical fp ops to ref)
    if (lane == 0) {
      s_tour[1 + step] = (unsigned short)nxt;
      lrbuf[step] = take ? lr : -1.0f;  // fire-and-forget global store
    }
    if (take) {
      float dwin = s_du[nxt].x;  // exact raw demand (read BEFORE INF mark)
      load = load - dwin;        // same fp op sequence as reference
      ntaken++;
      if (lane == 0) sduf[2 * nxt] = INF;
      if (lane == (nxt >> 5)) vmask |= 1u << (nxt & 31);
    } else {
      load = capf;
      if (ntaken == NN - 1) { ++step; break; }  // done: ref emits (depot,0) on
    }
    lasts = nxt;
    lr = load / capf;  // same fp32 division as reference
  }

  // ref emits (depot, 0) forever once done
  for (int q = step + lane; q < TSTEPS; q += 64) {
    s_tour[1 + q] = (unsigned short)depot;
    lrbuf[q] = -1.0f;
  }
  // drain all outstanding global stores (lrbuf) before reading them back
  asm volatile("s_waitcnt vmcnt(0)" ::: "memory");
  // ---- flush tour; compute scores exactly in a parallel deferred pass
  for (int i = lane; i <= TSTEPS; i += 64) out[i] = (float)s_tour[i];
  for (int s = lane; s < TSTEPS; s += 64) {
    float lrs = lrbuf[s];
    float sc = 0.0f;
    if (lrs >= 0.0f) {
      int lastI = (int)s_tour[s];
      int biI = (int)s_tour[s + 1];
      float g = GT[(size_t)lastI * NN + biI];
      sc = fmaf(s_du[biI].y, lrs, g) * C0;  // identical expression to R3-R15
    }
    out[1 + TSTEPS + s] = sc;
  }
}

extern "C" void kernel_launch(void* const* d_in, const int* in_sizes, int n_in,
                              void* d_out, int out_size, void* d_ws, size_t ws_size,
                              hipStream_t stream) {
  const float* emb     = (const float*)d_in[0];  // [N, H]
  const float* demands = (const float*)d_in[1];  // [N]
  const float* Wq      = (const float*)d_in[2];  // [H, H+2]
  const float* bq      = (const float*)d_in[3];  // [H]
  const float* Wk      = (const float*)d_in[4];  // [H, H]
  const float* bk      = (const float*)d_in[5];  // [H]
  const int* cap       = (const int*)d_in[6];
  const int* depot     = (const int*)d_in[7];
  float* out           = (float*)d_out;          // 2305 tour + 2304 scores, fp32

  char* ws = (char*)d_ws;
  float* Kmat = (float*)(ws);                         // 8 MB  [N,H]
  float* Z    = (float*)(ws + ((size_t)8 << 20));     // 8 MB  [N,H]
  float* GT   = (float*)(ws + ((size_t)16 << 20));    // 16 MB [N,N] row=last, +v
  float* Wqh  = (float*)(ws + ((size_t)32 << 20));    // 4 MB  [H,H]; later overlaid
  float* u    = (float*)(ws + ((size_t)36 << 20));    // 8 KB
  float* v    = (float*)(ws + ((size_t)36 << 20) + 8192);
  float* sink = (float*)(ws + ((size_t)36 << 20) + 32768);  // warm sink (unused)
  // overlays of the dead Wqh region (Wqh dead after the Z GEMM):
  uint2* cnd      = (uint2*)Wqh;                                       // 2 MB
  uint2* pc8g     = (uint2*)(ws + ((size_t)34 << 20));                 // 128 KB
  unsigned* thr8g = (unsigned*)(ws + ((size_t)34 << 20) + (128 << 10)); // 8 KB
  unsigned* thr2g = (unsigned*)(ws + ((size_t)34 << 20) + (136 << 10)); // 8 KB
  float* lrbuf    = (float*)(ws + ((size_t)34 << 20) + (144 << 10));    // 9.2 KB

  hipLaunchKernelGGL(prep_wqh, dim3(4096), dim3(256), 0, stream, Wq, Wqh);
  // K = emb @ Wk^T + bk
  hipLaunchKernelGGL(gemm_nt, dim3(HH / TILE, NN / TILE), dim3(256), 0, stream,
                     emb, HH, Wk, HH, Kmat, HH, HH, bk);
  // Z = emb @ Wqh^T
  hipLaunchKernelGGL(gemm_nt, dim3(HH / TILE, NN / TILE), dim3(256), 0, stream,
                     emb, HH, Wqh, HH, Z, HH, HH, (const float*)nullptr);
  // u_i = K_i . Wq[:,H], v_i = K_i . bq
  hipLaunchKernelGGL(uv_k, dim3(NN), dim3(64), 0, stream, Kmat, Wq, bq, u, v);
  // GT = Z @ K^T + v (v==0 since bq==0 -> bit-identical)
  hipLaunchKernelGGL(gemm_nt, dim3(NN / TILE, NN / TILE), dim3(256), 0, stream,
                     Z, HH, Kmat, HH, GT, NN, HH, v);
  // top-128 lists + fused top-8 entries + convex-bound thresholds
  hipLaunchKernelGGL(prep_cand, dim3(NN), dim3(256), 0, stream, GT, u, demands,
                     cnd, pc8g, thr8g, thr2g);
  // pre-warm LLC with cand (2 MB) + pc8/thr (152 KB) for the fallbacks
  hipLaunchKernelGGL(warm_k, dim3(128), dim3(256), 0, stream,
                     (const float*)cnd, NN * KCAND * 2 + (160 << 8), sink);
  hipLaunchKernelGGL(decode, dim3(1), dim3(64), 0, stream, GT, cnd,
                     pc8g, thr8g, thr2g, u, demands, cap, depot, lrbuf, out);
}

// Round 8
// 1956.171 us; speedup vs baseline: 1.1402x; 1.1402x over previous
//
#include <hip/hip_runtime.h>
#include <hip/hip_bf16.h>

// BeamDecoder: greedy CVRP-style decode.
// s_i(step) = c*( G[last,i] + (load/cap)*u_i )   (v==0 since bq==0; folded)
//
// R17: R16's KL8 fused entries regressed (1803us; FETCH+bank-conflicts show
// cert-rate collapse: thr8>thr15 and M1_8>M1_15 raise the convex bound ->
// far more tier-2). Reverted to R13 (proven 1308us). ONE structural change:
// HELPER-WAVE STAGER. Block = 128 threads (2 waves).
//  - wave 0: R13-verbatim decode. At step top, lane 0 publishes
//    seq=((step+1)<<11)|row to a volatile LDS mailbox (~20cyc, the only
//    cert-path cost).
//  - wave 1: spins on the mailbox; on new seq loads cand[row] (64 x uint4 =
//    full 1KB row), stages to LDS, lgkmcnt-drains, acks seq.
//  - wave 0 on cert miss: bounded poll of ack (<=6 volatile reads); hit ->
//    ds_read_b128 staged row (~120cyc) instead of the ~600-900cyc dependent
//    LLC load; miss -> R13-verbatim direct global load.
// Correctness never depends on wave 1 (no unbounded spin in wave 0; DONE
// sentinel released on every exit path; only __syncthreads is pre-split).
// Same-wave speculative VMEM is twice-proven harmful (R12,R14) -- this
// moves the latency to a wave whose time is free.
// Certification math = R13 verbatim (EGM covers 21-bit pack + t-key trunc;
// convex bounds B=(1-lr)*thrK+lr*M1_K+0.5 round-up bf16; flagged rows ->
// +inf -> always exact; ties fail margin -> exact fallback). Tier-2 exact
// 128-list; tier-3 R5-verbatim scan. Scores exact via deferred pass.

#define NN 2048
#define HH 1024
#define TSTEPS (NN + NN / 8)   // 2304
#define TILE 64
#define KT 16
#define KCAND 128
#define KL 15

// ---------------- pack Wq[:, :H] into ld=1024 buffer ----------------
__global__ __launch_bounds__(256) void prep_wqh(const float* __restrict__ Wq,
                                                float* __restrict__ Wqh) {
  int id = blockIdx.x * 256 + threadIdx.x;
  int r = id >> 10, c = id & 1023;
  Wqh[id] = Wq[r * (HH + 2) + c];
}

// ---------------- NT GEMM: C[M,N] = A[M,K] @ B[N,K]^T (+ bias[n]) ----------------
__global__ __launch_bounds__(256) void gemm_nt(const float* __restrict__ A, int lda,
                                               const float* __restrict__ B, int ldb,
                                               float* __restrict__ C, int ldc,
                                               int K, const float* __restrict__ bias) {
  __shared__ float As[KT][TILE + 4];
  __shared__ float Bs[KT][TILE + 4];
  const int i0 = blockIdx.y * TILE;
  const int j0 = blockIdx.x * TILE;
  const int t = threadIdx.x;
  const int srow = t >> 2, sq = t & 3;
  const int tx = t & 15, ty = t >> 4;
  float acc[4][4] = {};
  for (int k0 = 0; k0 < K; k0 += KT) {
    float4 av = *(const float4*)&A[(size_t)(i0 + srow) * lda + k0 + sq * 4];
    float4 bv = *(const float4*)&B[(size_t)(j0 + srow) * ldb + k0 + sq * 4];
    __syncthreads();
    As[sq * 4 + 0][srow] = av.x; As[sq * 4 + 1][srow] = av.y;
    As[sq * 4 + 2][srow] = av.z; As[sq * 4 + 3][srow] = av.w;
    Bs[sq * 4 + 0][srow] = bv.x; Bs[sq * 4 + 1][srow] = bv.y;
    Bs[sq * 4 + 2][srow] = bv.z; Bs[sq * 4 + 3][srow] = bv.w;
    __syncthreads();
#pragma unroll
    for (int k = 0; k < KT; ++k) {
      float4 a4 = *(const float4*)&As[k][ty * 4];
      float4 b4 = *(const float4*)&Bs[k][tx * 4];
      float a[4] = {a4.x, a4.y, a4.z, a4.w};
      float b[4] = {b4.x, b4.y, b4.z, b4.w};
#pragma unroll
      for (int m = 0; m < 4; ++m)
#pragma unroll
        for (int n = 0; n < 4; ++n) acc[m][n] = fmaf(a[m], b[n], acc[m][n]);
    }
  }
  float bb[4] = {0.f, 0.f, 0.f, 0.f};
  if (bias) {
#pragma unroll
    for (int n = 0; n < 4; ++n) bb[n] = bias[j0 + tx * 4 + n];
  }
#pragma unroll
  for (int m = 0; m < 4; ++m) {
    float4 st = {acc[m][0] + bb[0], acc[m][1] + bb[1], acc[m][2] + bb[2], acc[m][3] + bb[3]};
    *(float4*)&C[(size_t)(i0 + ty * 4 + m) * ldc + j0 + tx * 4] = st;
  }
}

// ---------------- u_i = K_i . Wq[:,H], v_i = K_i . bq  (one wave per row) ---------
__global__ __launch_bounds__(64) void uv_k(const float* __restrict__ Kmat,
                                           const float* __restrict__ Wq,
                                           const float* __restrict__ bq,
                                           float* __restrict__ u, float* __restrict__ v) {
  int i = blockIdx.x;
  int lane = threadIdx.x;
  float su = 0.f, sv = 0.f;
#pragma unroll
  for (int m = 0; m < HH / 64; ++m) {
    int j = lane + 64 * m;
    float kv = Kmat[(size_t)i * HH + j];
    su = fmaf(kv, Wq[(size_t)j * (HH + 2) + HH], su);
    sv = fmaf(kv, bq[j], sv);
  }
#pragma unroll
  for (int off = 32; off; off >>= 1) {
    su += __shfl_down(su, off, 64);
    sv += __shfl_down(sv, off, 64);
  }
  if (lane == 0) { u[i] = su; v[i] = sv; }
}

// ---------------- per-row exact top-K by g: 4-pass radix-select ----------------
__device__ __forceinline__ unsigned f2key(float f) {
  unsigned x = __float_as_uint(f);
  return x ^ ((x >> 31) ? 0xFFFFFFFFu : 0x80000000u);  // monotonic asc mapping
}
__device__ __forceinline__ float key2f(unsigned k) {
  unsigned x = (k & 0x80000000u) ? (k ^ 0x80000000u) : ~k;
  return __uint_as_float(x);
}
// bf16-style round-UP (toward +inf) of a float. ub16f(x) >= x always.
__device__ __forceinline__ unsigned ub16(float x) {
  unsigned b = __float_as_uint(x);
  if (x > 0.f && (b & 0xFFFFu)) b += 0x10000u;
  return b >> 16;
}
// Produces: cand[row][0..127] exact top-128 (value,idx); pc16[row][0..14]
// packed top-15 (key&~0x7FF | idx); thrpk2[row] = uint2:
//   .x = ub16(thr15)<<16 | ub16(M1_15)    (+inf halves when row flagged)
//   .y = ub16(thr128)<<16 | ub16(M1_128)
// where M1_K = max over j NOT in the stored top-K list of (g_j + u_j).
// Flag: any stored top-15 entry with |g|+|u| >= 128 (bounds both the 21-bit
// g-pack error and the decode-side t-key truncation error to <= 0.0156).
__global__ __launch_bounds__(256) void prep_cand(const float* __restrict__ GT,
                                                 const float* __restrict__ u,
                                                 uint2* __restrict__ cand,
                                                 unsigned* __restrict__ pc16,
                                                 uint2* __restrict__ thrpk2) {
  __shared__ float rowv[NN];
  __shared__ float su_[NN];
  __shared__ int hist[256];
  __shared__ float red15[256];
  __shared__ float red128[256];
  __shared__ unsigned c128k[KCAND];
  __shared__ int c128i[KCAND];
  __shared__ unsigned char markA[NN];  // in stored top-128
  __shared__ unsigned char markB[NN];  // in stored top-15
  __shared__ int s_d, s_need, s_gt, s_eq, s_gt2, s_eq2, s_flag;
  const int row = blockIdx.x, t = threadIdx.x;
  for (int i = t; i < NN; i += 256) {
    rowv[i] = GT[(size_t)row * NN + i];
    su_[i] = u[i];
    markA[i] = 0;
    markB[i] = 0;
  }
  __syncthreads();
  unsigned prefix = 0;
  int need = KCAND;
  for (int pass = 0; pass < 4; ++pass) {
    hist[t] = 0;
    __syncthreads();
    const int shift = 24 - 8 * pass;
    for (int i = t; i < NN; i += 256) {
      unsigned k = f2key(rowv[i]);
      if (pass == 0 || (k >> (shift + 8)) == (prefix >> (shift + 8)))
        atomicAdd(&hist[(k >> shift) & 0xFF], 1);
    }
    __syncthreads();
    if (t == 0) {
      int cum = 0, d = 255;
      for (; d > 0; --d) {
        if (cum + hist[d] >= need) break;
        cum += hist[d];
      }
      s_d = d;
      s_need = need - cum;
    }
    __syncthreads();
    prefix |= ((unsigned)s_d) << shift;
    need = s_need;
    __syncthreads();
  }
  const unsigned thrk = prefix;  // exact KCAND-th largest key
  if (t == 0) { s_gt = 0; s_eq = 0; }
  __syncthreads();
  for (int i = t; i < NN; i += 256) {
    unsigned k = f2key(rowv[i]);
    if (k > thrk) {
      int p = atomicAdd(&s_gt, 1);
      cand[(size_t)row * KCAND + p] = make_uint2(__float_as_uint(rowv[i]), (unsigned)i);
      c128k[p] = k;
      c128i[p] = i;
      markA[i] = 1;
    }
  }
  __syncthreads();
  const int cgt = s_gt;
  for (int i = t; i < NN; i += 256) {
    if (f2key(rowv[i]) == thrk) {
      int p = atomicAdd(&s_eq, 1);
      if (p < KCAND - cgt) {
        cand[(size_t)row * KCAND + cgt + p] = make_uint2(__float_as_uint(rowv[i]), (unsigned)i);
        c128k[cgt + p] = thrk;
        c128i[cgt + p] = i;
        markA[i] = 1;
      }
    }
  }
  __syncthreads();
  // ---- exact 15th-largest among the 128 keys (== row's top-15 multiset)
  unsigned pfx2 = 0;
  need = KL;
  for (int pass = 0; pass < 4; ++pass) {
    hist[t] = 0;
    __syncthreads();
    const int shift = 24 - 8 * pass;
    for (int i = t; i < KCAND; i += 256) {
      unsigned k = c128k[i];
      if (pass == 0 || (k >> (shift + 8)) == (pfx2 >> (shift + 8)))
        atomicAdd(&hist[(k >> shift) & 0xFF], 1);
    }
    __syncthreads();
    if (t == 0) {
      int cum = 0, d = 255;
      for (; d > 0; --d) {
        if (cum + hist[d] >= need) break;
        cum += hist[d];
      }
      s_d = d;
      s_need = need - cum;
    }
    __syncthreads();
    pfx2 |= ((unsigned)s_d) << shift;
    need = s_need;
    __syncthreads();
  }
  const unsigned thrk15 = pfx2;
  if (t == 0) { s_gt2 = 0; s_eq2 = 0; s_flag = 0; }
  __syncthreads();
  for (int i = t; i < KCAND; i += 256) {
    if (c128k[i] > thrk15) {
      int p = atomicAdd(&s_gt2, 1);
      pc16[(size_t)row * KL + p] = (c128k[i] & 0xFFFFF800u) | (unsigned)c128i[i];
      markB[c128i[i]] = 1;
      if (fabsf(key2f(c128k[i])) + fabsf(su_[c128i[i]]) >= 128.0f) s_flag = 1;
    }
  }
  __syncthreads();
  const int cgt2 = s_gt2;
  for (int i = t; i < KCAND; i += 256) {
    if (c128k[i] == thrk15) {
      int p = atomicAdd(&s_eq2, 1);
      if (p < KL - cgt2) {
        pc16[(size_t)row * KL + cgt2 + p] = (thrk15 & 0xFFFFF800u) | (unsigned)c128i[i];
        markB[c128i[i]] = 1;
        if (fabsf(key2f(thrk15)) + fabsf(su_[c128i[i]]) >= 128.0f) s_flag = 1;
      }
    }
  }
  if (t == 0 && fabsf(key2f(thrk15)) >= 128.0f) s_flag = 1;
  __syncthreads();
  // ---- M1_15 / M1_128: max of (g + u) over nodes outside each stored list
  float lm15 = -__builtin_inff(), lm128 = -__builtin_inff();
  for (int i = t; i < NN; i += 256) {
    float gu = rowv[i] + su_[i];
    if (!markB[i]) lm15 = fmaxf(lm15, gu);
    if (!markA[i]) lm128 = fmaxf(lm128, gu);
  }
  red15[t] = lm15;
  red128[t] = lm128;
  __syncthreads();
  for (int s = 128; s; s >>= 1) {
    if (t < s) {
      red15[t] = fmaxf(red15[t], red15[t + s]);
      red128[t] = fmaxf(red128[t], red128[t + s]);
    }
    __syncthreads();
  }
  if (t == 0) {
    const float INF = __builtin_inff();
    float t15 = s_flag ? INF : key2f(thrk15);
    float m15 = s_flag ? INF : red15[0];
    thrpk2[row] = make_uint2((ub16(t15) << 16) | ub16(m15),
                             (ub16(key2f(thrk)) << 16) | ub16(red128[0]));
  }
}

// ---------------- LLC pre-warm for the tier-2 fallback lists ---------------------
__global__ __launch_bounds__(256) void warm_k(const float* __restrict__ a, int n,
                                              float* __restrict__ sink) {
  float s = 0.f;
  const float4* a4 = (const float4*)a;
  for (int i = threadIdx.x; i < n / 4; i += 256) {
    float4 x = a4[i];
    s += x.x + x.y + x.z + x.w;
  }
  if (s == 1.2345e-30f) sink[blockIdx.x] = s;  // never true; keeps loads alive
}

// DPP merge of (bv,bi): max value, smallest index on ties. Invalid lanes get
// (-inf, INT_MAX).
#define DPP_MERGE2(CTRL)                                                      \
  {                                                                           \
    int ovb = __builtin_amdgcn_update_dpp(                                    \
        (int)0xFF800000, __float_as_int(bv), (CTRL), 0xf, 0xf, false);        \
    int oib = __builtin_amdgcn_update_dpp(                                    \
        0x7fffffff, bi, (CTRL), 0xf, 0xf, false);                             \
    float ov = __int_as_float(ovb);                                           \
    if (ov > bv || (ov == bv && oib < bi)) { bv = ov; bi = oib; }             \
  }

// Packed u32 max + runner-up over a 16-lane DPP row. m1 = max key,
// m2 = runner-up key of the union. key 0 = invalid sentinel.
#define KRED(CTRL)                                                            \
  {                                                                           \
    unsigned o1 = (unsigned)__builtin_amdgcn_update_dpp(                      \
        0, (int)m1, (CTRL), 0xf, 0xf, false);                                 \
    unsigned o2 = (unsigned)__builtin_amdgcn_update_dpp(                      \
        0, (int)m2, (CTRL), 0xf, 0xf, false);                                 \
    unsigned mn = min(m1, o1);                                                \
    m1 = max(m1, o1);                                                         \
    m2 = max(max(m2, o2), mn);                                                \
  }

struct Pick { int take; int nxt; };

// Tier-3: R5-verbatim exact full-row scan. Cold; kept out of the hot loop's
// instruction stream.
__device__ __noinline__ Pick tier3_scan(const float* __restrict__ GT,
                                        const float2* sdu, int row, int lane,
                                        float load, float lr, int depot) {
  const float NEGINF = -__builtin_inff();
  const float4* rowp = (const float4*)(GT + (size_t)row * NN);
  const float4* du4 = (const float4*)sdu;
  float fv = NEGINF;
  int fi = NN;
#pragma unroll
  for (int r = 0; r < 8; ++r) {
    float4 g4 = rowp[r * 64 + lane];
    float4 pA = du4[(r * 64 + lane) * 2];      // d0,u0,d1,u1
    float4 pB = du4[(r * 64 + lane) * 2 + 1];  // d2,u2,d3,u3
    float gl[4] = {g4.x, g4.y, g4.z, g4.w};
    float dl[4] = {pA.x, pA.z, pB.x, pB.z};
    float ul[4] = {pA.y, pA.w, pB.y, pB.w};
    float cv = NEGINF;
    int cj = 0;
#pragma unroll
    for (int j = 0; j < 4; ++j) {
      float tt = fmaf(ul[j], lr, gl[j]);
      bool feas = (dl[j] <= load);
      if (feas && tt > cv) { cv = tt; cj = j; }
    }
    if (cv > fv) { fv = cv; fi = 4 * (r * 64 + lane) + cj; }  // asc r: first-max
  }
  float bv = fv;
  int bi = fi;
  DPP_MERGE2(0x111); DPP_MERGE2(0x112); DPP_MERGE2(0x114);
  DPP_MERGE2(0x118); DPP_MERGE2(0x142); DPP_MERGE2(0x143);
  float fbv = __int_as_float(__builtin_amdgcn_readlane(__float_as_int(bv), 63));
  int fbi = __builtin_amdgcn_readlane(bi, 63);
  Pick p;
  p.take = (fbv > NEGINF) ? 1 : 0;
  p.nxt = p.take ? fbi : depot;
  return p;
}

// ---------------- sequential decode: wave 0 decodes, wave 1 stages ---------------
__global__ __launch_bounds__(128, 1) void decode(const float* __restrict__ GT,
                                                 const uint2* __restrict__ cand,
                                                 const unsigned* __restrict__ pc16,
                                                 const uint2* __restrict__ thrpk2,
                                                 const float* __restrict__ u,
                                                 const float* __restrict__ demands,
                                                 const int* __restrict__ capp,
                                                 const int* __restrict__ depotp,
                                                 float* __restrict__ lrbuf,
                                                 float* __restrict__ out) {
  __shared__ __align__(16) unsigned s_pc[NN * KL + 64];   // 123.1 KB packed lists
  __shared__ __align__(16) float2 s_du[NN];               // 16 KB (.x=d|+inf, .y=u)
  __shared__ __align__(16) uint2 s_thr[NN];               // 16 KB packed thresholds
  __shared__ __align__(16) unsigned short s_tour[TSTEPS + 2];  // 4.6 KB
  __shared__ __align__(16) uint4 s_stage[64];             // 1 KB staged cand row
  __shared__ volatile int s_req;                          // mailbox: seq|row
  __shared__ volatile int s_ack;                          // staged seq

  const int tid = threadIdx.x;
  const int lane = tid & 63;
  const int depot = *depotp;
  const float capf = (float)(*capp);
  const float INF = __builtin_inff();
  const float C0 = 0.015625f;   // ALPHA / sqrt(HID), exact power of two
  const float MARGIN = 0.5f;    // >> any fp32 rounding in the bounds
  const float EGM = 0.0625f;    // > pack err 0.0156 + t-key trunc 0.0156 + rounding
  float* sduf = (float*)s_du;

  for (int i = tid; i < NN; i += 128) {
    s_du[i] = make_float2(demands[i], u[i]);
    s_thr[i] = thrpk2[i];
  }
  {
    const uint4* p4 = (const uint4*)pc16;
    uint4* q4 = (uint4*)s_pc;
    for (int i = tid; i < NN * KL / 4; i += 128) q4[i] = p4[i];
  }
  if (tid == 0) {
    sduf[2 * depot] = INF;  // depot starts visited
    s_tour[0] = (unsigned short)depot;
    s_req = 0;
    s_ack = 0;
  }
  __syncthreads();  // both waves present exactly once; they diverge after this

  if (tid >= 64) {
    // ---------------- wave 1: stager ----------------
    int last = 0;
    for (;;) {
      int rq = s_req;          // volatile LDS poll
      if (rq == last) continue;
      if (rq == -1) return;    // DONE sentinel
      last = rq;
      int row = rq & (NN - 1);
      uint4 c = ((const uint4*)(cand + (size_t)row * KCAND))[lane];
      s_stage[lane] = c;       // compiler inserts vmcnt wait before this
      asm volatile("s_waitcnt lgkmcnt(0)" ::: "memory");
      __builtin_amdgcn_sched_barrier(0);
      s_ack = rq;              // publish completion AFTER stage writes retired
    }
  }

  // ---------------- wave 0: decode (R13-verbatim tiers) ----------------
  int ntaken = 0, lasts = depot;
  float load = capf;
  float lr = load / capf;  // same fp32 division as reference
  int step = 0;
  const int lcl = (lane < KL) ? lane : (KL - 1);  // lanes >=15 duplicate entry 14

  for (; step < TSTEPS; ++step) {
    const int row = lasts;
    const int seq = ((step + 1) << 11) | row;
    if (lane == 0) s_req = seq;  // publish to stager (~20cyc, fire-and-forget)
    // ---- tier-1: 15 packed candidates, lanes 0-14 (pure LDS + VALU)
    unsigned pw = s_pc[row * KL + lcl];
    uint2 pk2 = s_thr[row];
    int i1x = (int)(pw & 0x7FFu);
    float2 du1 = s_du[i1x];              // dependent gather (ds_read_b64)
    float g1 = key2f(pw & 0xFFFFF800u);  // ghat <= g <= ghat + 0.0156
    float t1 = fmaf(du1.y, lr, g1);
    bool act = (lane < KL) && (du1.x <= load);
    unsigned m1 = act ? ((f2key(t1) & 0xFFFFF800u) | ((~(unsigned)i1x) & 0x7FFu)) : 0u;
    unsigned m2 = 0u;
    KRED(0x111); KRED(0x112); KRED(0x114); KRED(0x118);
    unsigned rv1k = (unsigned)__builtin_amdgcn_readlane((int)m1, 15);
    unsigned rv2k = (unsigned)__builtin_amdgcn_readlane((int)m2, 15);
    float rv1f = key2f(rv1k & 0xFFFFF800u);  // round-down: lower bd of winner t
    float rv2f = key2f(rv2k | 0x7FFu);       // round-up: upper bd of runner-up
    float t15 = __uint_as_float(pk2.x & 0xFFFF0000u);
    float m15 = __uint_as_float(pk2.x << 16);
    float B1 = fmaf(1.0f - lr, t15, lr * m15) + MARGIN;  // convex outside bound
    int take, nxt;
    if (__builtin_expect((rv1f > B1) && (rv1f > rv2f + EGM), 1)) {
      // certified: true t_w >= rv1f; rv1f > rv2f+EGM beats every other
      // in-list true t (trunc+pack err < EGM); rv1f > B1 beats every outside
      // node at this lr. Unique argmax == ref's pick. (No feasible cand ->
      // rv1k==0 -> rv1f NaN -> both compares false -> fallback.)
      take = 1;
      nxt = (int)((~rv1k) & 0x7FFu);
    } else {
      // ---- tier-2: staged row if the helper finished; else direct load
      uint4 cc;
      int got = 0;
#pragma unroll 1
      for (int z = 0; z < 6; ++z) {
        if (s_ack == seq) { got = 1; break; }   // bounded volatile poll
      }
      if (got) {
        asm volatile("s_waitcnt lgkmcnt(0)" ::: "memory");
        __builtin_amdgcn_sched_barrier(0);
        cc = s_stage[lane];   // ~120cyc LDS vs ~600-900cyc LLC
      } else {
        cc = ((const uint4*)(cand + (size_t)row * KCAND))[lane];
      }
      float bv = -INF;
      int bi = 0x7fffffff;
      {
        float ga = __uint_as_float(cc.x); int ia = (int)cc.y;
        float gb = __uint_as_float(cc.z); int ib = (int)cc.w;
        float2 da = s_du[ia];
        float2 db = s_du[ib];
        float ta = fmaf(da.y, lr, ga);
        float tb = fmaf(db.y, lr, gb);
        if ((da.x <= load) && (ta > bv || (ta == bv && ia < bi))) { bv = ta; bi = ia; }
        if ((db.x <= load) && (tb > bv || (tb == bv && ib < bi))) { bv = tb; bi = ib; }
      }
      DPP_MERGE2(0x111); DPP_MERGE2(0x112); DPP_MERGE2(0x114);
      DPP_MERGE2(0x118); DPP_MERGE2(0x142); DPP_MERGE2(0x143);
      float rbv = __int_as_float(__builtin_amdgcn_readlane(__float_as_int(bv), 63));
      int rbi = __builtin_amdgcn_readlane(bi, 63);
      float t128 = __uint_as_float(pk2.y & 0xFFFF0000u);
      float m128 = __uint_as_float(pk2.y << 16);
      float B2 = fmaf(1.0f - lr, t128, lr * m128) + MARGIN;
      if (rbv > B2) {
        take = 1; nxt = rbi;
      } else {
        Pick p = tier3_scan(GT, (const float2*)s_du, row, lane, load, lr, depot);
        take = p.take; nxt = p.nxt;
      }
    }

    // ---- state update + output stores (identical fp ops to ref)
    if (lane == 0) {
      s_tour[1 + step] = (unsigned short)nxt;
      lrbuf[step] = take ? lr : -1.0f;  // fire-and-forget global store
    }
    if (take) {
      float dwin = s_du[nxt].x;  // raw demand (read BEFORE the INF mark below)
      load = load - dwin;        // same fp op sequence as reference
      ntaken++;
      if (lane == 0) sduf[2 * nxt] = INF;
    } else {
      load = capf;
      if (ntaken == NN - 1) { ++step; break; }  // done: ref emits (depot,0) on
    }
    lasts = nxt;
    lr = load / capf;  // same fp32 division as reference
  }

  if (lane == 0) s_req = -1;  // release the stager wave (every exit path)

  // ref emits (depot, 0) forever once done
  for (int q = step + lane; q < TSTEPS; q += 64) {
    s_tour[1 + q] = (unsigned short)depot;
    lrbuf[q] = -1.0f;
  }
  // drain all outstanding global stores (lrbuf) before reading them back
  asm volatile("s_waitcnt vmcnt(0)" ::: "memory");
  // ---- flush tour; compute scores exactly in a parallel deferred pass
  for (int i = lane; i <= TSTEPS; i += 64) out[i] = (float)s_tour[i];
  for (int s = lane; s < TSTEPS; s += 64) {
    float lrs = lrbuf[s];
    float sc = 0.0f;
    if (lrs >= 0.0f) {
      int lastI = (int)s_tour[s];
      int biI = (int)s_tour[s + 1];
      float g = GT[(size_t)lastI * NN + biI];
      sc = fmaf(s_du[biI].y, lrs, g) * C0;  // identical expression to R3-R16
    }
    out[1 + TSTEPS + s] = sc;
  }
}

extern "C" void kernel_launch(void* const* d_in, const int* in_sizes, int n_in,
                              void* d_out, int out_size, void* d_ws, size_t ws_size,
                              hipStream_t stream) {
  const float* emb     = (const float*)d_in[0];  // [N, H]
  const float* demands = (const float*)d_in[1];  // [N]
  const float* Wq      = (const float*)d_in[2];  // [H, H+2]
  const float* bq      = (const float*)d_in[3];  // [H]
  const float* Wk      = (const float*)d_in[4];  // [H, H]
  const float* bk      = (const float*)d_in[5];  // [H]
  const int* cap       = (const int*)d_in[6];
  const int* depot     = (const int*)d_in[7];
  float* out           = (float*)d_out;          // 2305 tour + 2304 scores, fp32

  char* ws = (char*)d_ws;
  float* Kmat = (float*)(ws);                         // 8 MB  [N,H]
  float* Z    = (float*)(ws + ((size_t)8 << 20));     // 8 MB  [N,H]
  float* GT   = (float*)(ws + ((size_t)16 << 20));    // 16 MB [N,N] row=last, +v
  float* Wqh  = (float*)(ws + ((size_t)32 << 20));    // 4 MB  [H,H]; later overlaid
  float* u    = (float*)(ws + ((size_t)36 << 20));    // 8 KB
  float* v    = (float*)(ws + ((size_t)36 << 20) + 8192);
  float* sink = (float*)(ws + ((size_t)36 << 20) + 32768);  // warm sink (unused)
  // overlays of the dead Wqh region (Wqh dead after the Z GEMM):
  uint2* cnd  = (uint2*)Wqh;                                        // 2 MB
  unsigned* pc16g = (unsigned*)(ws + ((size_t)34 << 20));           // 120 KB
  uint2* thrpk2g  = (uint2*)(ws + ((size_t)34 << 20) + (128 << 10)); // 16 KB
  float* lrbuf    = (float*)(ws + ((size_t)34 << 20) + (160 << 10)); // 9.2 KB

  hipLaunchKernelGGL(prep_wqh, dim3(4096), dim3(256), 0, stream, Wq, Wqh);
  // K = emb @ Wk^T + bk
  hipLaunchKernelGGL(gemm_nt, dim3(HH / TILE, NN / TILE), dim3(256), 0, stream,
                     emb, HH, Wk, HH, Kmat, HH, HH, bk);
  // Z = emb @ Wqh^T
  hipLaunchKernelGGL(gemm_nt, dim3(HH / TILE, NN / TILE), dim3(256), 0, stream,
                     emb, HH, Wqh, HH, Z, HH, HH, (const float*)nullptr);
  // u_i = K_i . Wq[:,H], v_i = K_i . bq
  hipLaunchKernelGGL(uv_k, dim3(NN), dim3(64), 0, stream, Kmat, Wq, bq, u, v);
  // GT = Z @ K^T + v (v==0 since bq==0 -> bit-identical)
  hipLaunchKernelGGL(gemm_nt, dim3(NN / TILE, NN / TILE), dim3(256), 0, stream,
                     Z, HH, Kmat, HH, GT, NN, HH, v);
  // top-128 lists + packed top-15 + convex-bound thresholds (overlay dead Wqh)
  hipLaunchKernelGGL(prep_cand, dim3(NN), dim3(256), 0, stream, GT, u, cnd,
                     pc16g, thrpk2g);
  // pre-warm LLC with cand (2 MB) + pc16/thr for the fallbacks
  hipLaunchKernelGGL(warm_k, dim3(128), dim3(256), 0, stream,
                     (const float*)cnd, NN * KCAND * 2 + (160 << 8), sink);
  hipLaunchKernelGGL(decode, dim3(1), dim3(128), 0, stream, GT, cnd,
                     pc16g, thrpk2g, u, demands, cap, depot, lrbuf, out);
}

// Round 9
// 1841.655 us; speedup vs baseline: 1.2111x; 1.0622x over previous
//
#include <hip/hip_runtime.h>
#include <hip/hip_bf16.h>

// BeamDecoder: greedy CVRP-style decode.
// s_i(step) = c*( G[last,i] + (load/cap)*u_i )   (v==0 since bq==0; folded)
//
// R18: R17's helper-wave stager regressed (1415us; stager spin hammers the
// LDS port + per-step mailbox cost; FETCH shows every-step staging like
// R12/R14). Third data point: per-step speculative staging loses to the
// ~8-15% tier-2 rate it serves. Decode reverted BYTE-FOR-BYTE to R13
// (proven 1308us) -- its serial chain is the floor for this shape.
// This round attacks the OTHER ~529us (total 1837 - decode 1308): the
// three fp32 GEMMs (17.2 GFLOP) ran on a 64^2-tile/4x4-acc kernel
// (FMA:LDS 8:1, ~35-45 TF). Changes (both preserve bit-exactness: each
// output's FMA chain remains ONE accumulator over strictly-ascending k,
// so GT/Kmat/Z are bit-identical; only tiling/parallelism changes):
//  (1) 128^2-tile / 8x8-acc GEMM (FMA:LDS 16:1, 64 indep FMAs/k) for all
//      three GEMMs; GT grid = 16x16 = 256 blocks = full GPU.
//  (2) K and Z are independent -> fused into ONE dispatch, grid (8,16,2)
//      = 256 blocks (was 2 x 128-block half-GPU launches).
// Decode/cert math unchanged from R13 (EGM margin, convex bounds, tiers).

#define NN 2048
#define HH 1024
#define TSTEPS (NN + NN / 8)   // 2304
#define GT2 128                // GEMM tile
#define KT 16
#define KCAND 128
#define KL 15

// ---------------- pack Wq[:, :H] into ld=1024 buffer ----------------
__global__ __launch_bounds__(256) void prep_wqh(const float* __restrict__ Wq,
                                                float* __restrict__ Wqh) {
  int id = blockIdx.x * 256 + threadIdx.x;
  int r = id >> 10, c = id & 1023;
  Wqh[id] = Wq[r * (HH + 2) + c];
}

// ---------------- NT GEMM body: C[128,128] tile = A[M,K] @ B[N,K]^T (+bias) ------
// Each output element's accumulation is a single FMA chain over ascending k
// (k0 tiles of KT, inner k 0..KT-1) -- bit-identical to the previous 64^2
// kernel's per-element arithmetic.
__device__ __forceinline__ void gemm_body(const float* __restrict__ A, int lda,
                                          const float* __restrict__ B, int ldb,
                                          float* __restrict__ C, int ldc,
                                          int K, const float* __restrict__ bias,
                                          int i0, int j0) {
  __shared__ float As[KT][GT2 + 4];
  __shared__ float Bs[KT][GT2 + 4];
  const int t = threadIdx.x;
  const int srow = t >> 2, sq = t & 3;
  const int tx = t & 15, ty = t >> 4;
  float acc[8][8] = {};
  for (int k0 = 0; k0 < K; k0 += KT) {
    float4 a0 = *(const float4*)&A[(size_t)(i0 + srow) * lda + k0 + sq * 4];
    float4 a1 = *(const float4*)&A[(size_t)(i0 + 64 + srow) * lda + k0 + sq * 4];
    float4 b0 = *(const float4*)&B[(size_t)(j0 + srow) * ldb + k0 + sq * 4];
    float4 b1 = *(const float4*)&B[(size_t)(j0 + 64 + srow) * ldb + k0 + sq * 4];
    __syncthreads();
    As[sq * 4 + 0][srow] = a0.x; As[sq * 4 + 1][srow] = a0.y;
    As[sq * 4 + 2][srow] = a0.z; As[sq * 4 + 3][srow] = a0.w;
    As[sq * 4 + 0][64 + srow] = a1.x; As[sq * 4 + 1][64 + srow] = a1.y;
    As[sq * 4 + 2][64 + srow] = a1.z; As[sq * 4 + 3][64 + srow] = a1.w;
    Bs[sq * 4 + 0][srow] = b0.x; Bs[sq * 4 + 1][srow] = b0.y;
    Bs[sq * 4 + 2][srow] = b0.z; Bs[sq * 4 + 3][srow] = b0.w;
    Bs[sq * 4 + 0][64 + srow] = b1.x; Bs[sq * 4 + 1][64 + srow] = b1.y;
    Bs[sq * 4 + 2][64 + srow] = b1.z; Bs[sq * 4 + 3][64 + srow] = b1.w;
    __syncthreads();
#pragma unroll
    for (int k = 0; k < KT; ++k) {
      float4 x0 = *(const float4*)&As[k][ty * 8];
      float4 x1 = *(const float4*)&As[k][ty * 8 + 4];
      float4 y0 = *(const float4*)&Bs[k][tx * 8];
      float4 y1 = *(const float4*)&Bs[k][tx * 8 + 4];
      float a[8] = {x0.x, x0.y, x0.z, x0.w, x1.x, x1.y, x1.z, x1.w};
      float b[8] = {y0.x, y0.y, y0.z, y0.w, y1.x, y1.y, y1.z, y1.w};
#pragma unroll
      for (int m = 0; m < 8; ++m)
#pragma unroll
        for (int n = 0; n < 8; ++n) acc[m][n] = fmaf(a[m], b[n], acc[m][n]);
    }
  }
  float bb[8] = {0.f, 0.f, 0.f, 0.f, 0.f, 0.f, 0.f, 0.f};
  if (bias) {
#pragma unroll
    for (int n = 0; n < 8; ++n) bb[n] = bias[j0 + tx * 8 + n];
  }
#pragma unroll
  for (int m = 0; m < 8; ++m) {
    float4 s0 = {acc[m][0] + bb[0], acc[m][1] + bb[1],
                 acc[m][2] + bb[2], acc[m][3] + bb[3]};
    float4 s1 = {acc[m][4] + bb[4], acc[m][5] + bb[5],
                 acc[m][6] + bb[6], acc[m][7] + bb[7]};
    *(float4*)&C[(size_t)(i0 + ty * 8 + m) * ldc + j0 + tx * 8] = s0;
    *(float4*)&C[(size_t)(i0 + ty * 8 + m) * ldc + j0 + tx * 8 + 4] = s1;
  }
}

// single GEMM (used for GT)
__global__ __launch_bounds__(256) void gemm_nt128(const float* __restrict__ A, int lda,
                                                  const float* __restrict__ B, int ldb,
                                                  float* __restrict__ C, int ldc,
                                                  int K, const float* __restrict__ bias) {
  gemm_body(A, lda, B, ldb, C, ldc, K, bias, blockIdx.y * GT2, blockIdx.x * GT2);
}

// fused K & Z GEMMs (independent; one full-GPU dispatch instead of two half)
__global__ __launch_bounds__(256) void gemm_kz(const float* __restrict__ emb,
                                               const float* __restrict__ Wk,
                                               const float* __restrict__ Wqh,
                                               const float* __restrict__ bk,
                                               float* __restrict__ Kmat,
                                               float* __restrict__ Z) {
  if (blockIdx.z == 0) {
    gemm_body(emb, HH, Wk, HH, Kmat, HH, HH, bk,
              blockIdx.y * GT2, blockIdx.x * GT2);
  } else {
    gemm_body(emb, HH, Wqh, HH, Z, HH, HH, (const float*)nullptr,
              blockIdx.y * GT2, blockIdx.x * GT2);
  }
}

// ---------------- u_i = K_i . Wq[:,H], v_i = K_i . bq  (one wave per row) ---------
__global__ __launch_bounds__(64) void uv_k(const float* __restrict__ Kmat,
                                           const float* __restrict__ Wq,
                                           const float* __restrict__ bq,
                                           float* __restrict__ u, float* __restrict__ v) {
  int i = blockIdx.x;
  int lane = threadIdx.x;
  float su = 0.f, sv = 0.f;
#pragma unroll
  for (int m = 0; m < HH / 64; ++m) {
    int j = lane + 64 * m;
    float kv = Kmat[(size_t)i * HH + j];
    su = fmaf(kv, Wq[(size_t)j * (HH + 2) + HH], su);
    sv = fmaf(kv, bq[j], sv);
  }
#pragma unroll
  for (int off = 32; off; off >>= 1) {
    su += __shfl_down(su, off, 64);
    sv += __shfl_down(sv, off, 64);
  }
  if (lane == 0) { u[i] = su; v[i] = sv; }
}

// ---------------- per-row exact top-K by g: 4-pass radix-select ----------------
__device__ __forceinline__ unsigned f2key(float f) {
  unsigned x = __float_as_uint(f);
  return x ^ ((x >> 31) ? 0xFFFFFFFFu : 0x80000000u);  // monotonic asc mapping
}
__device__ __forceinline__ float key2f(unsigned k) {
  unsigned x = (k & 0x80000000u) ? (k ^ 0x80000000u) : ~k;
  return __uint_as_float(x);
}
// bf16-style round-UP (toward +inf) of a float. ub16f(x) >= x always.
__device__ __forceinline__ unsigned ub16(float x) {
  unsigned b = __float_as_uint(x);
  if (x > 0.f && (b & 0xFFFFu)) b += 0x10000u;
  return b >> 16;
}
// Produces: cand[row][0..127] exact top-128 (value,idx); pc16[row][0..14]
// packed top-15 (key&~0x7FF | idx); thrpk2[row] = uint2:
//   .x = ub16(thr15)<<16 | ub16(M1_15)    (+inf halves when row flagged)
//   .y = ub16(thr128)<<16 | ub16(M1_128)
// where M1_K = max over j NOT in the stored top-K list of (g_j + u_j).
// Flag: any stored top-15 entry with |g|+|u| >= 128 (bounds both the 21-bit
// g-pack error and the decode-side t-key truncation error to <= 0.0156).
__global__ __launch_bounds__(256) void prep_cand(const float* __restrict__ GT,
                                                 const float* __restrict__ u,
                                                 uint2* __restrict__ cand,
                                                 unsigned* __restrict__ pc16,
                                                 uint2* __restrict__ thrpk2) {
  __shared__ float rowv[NN];
  __shared__ float su_[NN];
  __shared__ int hist[256];
  __shared__ float red15[256];
  __shared__ float red128[256];
  __shared__ unsigned c128k[KCAND];
  __shared__ int c128i[KCAND];
  __shared__ unsigned char markA[NN];  // in stored top-128
  __shared__ unsigned char markB[NN];  // in stored top-15
  __shared__ int s_d, s_need, s_gt, s_eq, s_gt2, s_eq2, s_flag;
  const int row = blockIdx.x, t = threadIdx.x;
  for (int i = t; i < NN; i += 256) {
    rowv[i] = GT[(size_t)row * NN + i];
    su_[i] = u[i];
    markA[i] = 0;
    markB[i] = 0;
  }
  __syncthreads();
  unsigned prefix = 0;
  int need = KCAND;
  for (int pass = 0; pass < 4; ++pass) {
    hist[t] = 0;
    __syncthreads();
    const int shift = 24 - 8 * pass;
    for (int i = t; i < NN; i += 256) {
      unsigned k = f2key(rowv[i]);
      if (pass == 0 || (k >> (shift + 8)) == (prefix >> (shift + 8)))
        atomicAdd(&hist[(k >> shift) & 0xFF], 1);
    }
    __syncthreads();
    if (t == 0) {
      int cum = 0, d = 255;
      for (; d > 0; --d) {
        if (cum + hist[d] >= need) break;
        cum += hist[d];
      }
      s_d = d;
      s_need = need - cum;
    }
    __syncthreads();
    prefix |= ((unsigned)s_d) << shift;
    need = s_need;
    __syncthreads();
  }
  const unsigned thrk = prefix;  // exact KCAND-th largest key
  if (t == 0) { s_gt = 0; s_eq = 0; }
  __syncthreads();
  for (int i = t; i < NN; i += 256) {
    unsigned k = f2key(rowv[i]);
    if (k > thrk) {
      int p = atomicAdd(&s_gt, 1);
      cand[(size_t)row * KCAND + p] = make_uint2(__float_as_uint(rowv[i]), (unsigned)i);
      c128k[p] = k;
      c128i[p] = i;
      markA[i] = 1;
    }
  }
  __syncthreads();
  const int cgt = s_gt;
  for (int i = t; i < NN; i += 256) {
    if (f2key(rowv[i]) == thrk) {
      int p = atomicAdd(&s_eq, 1);
      if (p < KCAND - cgt) {
        cand[(size_t)row * KCAND + cgt + p] = make_uint2(__float_as_uint(rowv[i]), (unsigned)i);
        c128k[cgt + p] = thrk;
        c128i[cgt + p] = i;
        markA[i] = 1;
      }
    }
  }
  __syncthreads();
  // ---- exact 15th-largest among the 128 keys (== row's top-15 multiset)
  unsigned pfx2 = 0;
  need = KL;
  for (int pass = 0; pass < 4; ++pass) {
    hist[t] = 0;
    __syncthreads();
    const int shift = 24 - 8 * pass;
    for (int i = t; i < KCAND; i += 256) {
      unsigned k = c128k[i];
      if (pass == 0 || (k >> (shift + 8)) == (pfx2 >> (shift + 8)))
        atomicAdd(&hist[(k >> shift) & 0xFF], 1);
    }
    __syncthreads();
    if (t == 0) {
      int cum = 0, d = 255;
      for (; d > 0; --d) {
        if (cum + hist[d] >= need) break;
        cum += hist[d];
      }
      s_d = d;
      s_need = need - cum;
    }
    __syncthreads();
    pfx2 |= ((unsigned)s_d) << shift;
    need = s_need;
    __syncthreads();
  }
  const unsigned thrk15 = pfx2;
  if (t == 0) { s_gt2 = 0; s_eq2 = 0; s_flag = 0; }
  __syncthreads();
  for (int i = t; i < KCAND; i += 256) {
    if (c128k[i] > thrk15) {
      int p = atomicAdd(&s_gt2, 1);
      pc16[(size_t)row * KL + p] = (c128k[i] & 0xFFFFF800u) | (unsigned)c128i[i];
      markB[c128i[i]] = 1;
      if (fabsf(key2f(c128k[i])) + fabsf(su_[c128i[i]]) >= 128.0f) s_flag = 1;
    }
  }
  __syncthreads();
  const int cgt2 = s_gt2;
  for (int i = t; i < KCAND; i += 256) {
    if (c128k[i] == thrk15) {
      int p = atomicAdd(&s_eq2, 1);
      if (p < KL - cgt2) {
        pc16[(size_t)row * KL + cgt2 + p] = (thrk15 & 0xFFFFF800u) | (unsigned)c128i[i];
        markB[c128i[i]] = 1;
        if (fabsf(key2f(thrk15)) + fabsf(su_[c128i[i]]) >= 128.0f) s_flag = 1;
      }
    }
  }
  if (t == 0 && fabsf(key2f(thrk15)) >= 128.0f) s_flag = 1;
  __syncthreads();
  // ---- M1_15 / M1_128: max of (g + u) over nodes outside each stored list
  float lm15 = -__builtin_inff(), lm128 = -__builtin_inff();
  for (int i = t; i < NN; i += 256) {
    float gu = rowv[i] + su_[i];
    if (!markB[i]) lm15 = fmaxf(lm15, gu);
    if (!markA[i]) lm128 = fmaxf(lm128, gu);
  }
  red15[t] = lm15;
  red128[t] = lm128;
  __syncthreads();
  for (int s = 128; s; s >>= 1) {
    if (t < s) {
      red15[t] = fmaxf(red15[t], red15[t + s]);
      red128[t] = fmaxf(red128[t], red128[t + s]);
    }
    __syncthreads();
  }
  if (t == 0) {
    const float INF = __builtin_inff();
    float t15 = s_flag ? INF : key2f(thrk15);
    float m15 = s_flag ? INF : red15[0];
    thrpk2[row] = make_uint2((ub16(t15) << 16) | ub16(m15),
                             (ub16(key2f(thrk)) << 16) | ub16(red128[0]));
  }
}

// ---------------- LLC pre-warm for the tier-2 fallback lists ---------------------
__global__ __launch_bounds__(256) void warm_k(const float* __restrict__ a, int n,
                                              float* __restrict__ sink) {
  float s = 0.f;
  const float4* a4 = (const float4*)a;
  for (int i = threadIdx.x; i < n / 4; i += 256) {
    float4 x = a4[i];
    s += x.x + x.y + x.z + x.w;
  }
  if (s == 1.2345e-30f) sink[blockIdx.x] = s;  // never true; keeps loads alive
}

// DPP merge of (bv,bi): max value, smallest index on ties. Invalid lanes get
// (-inf, INT_MAX).
#define DPP_MERGE2(CTRL)                                                      \
  {                                                                           \
    int ovb = __builtin_amdgcn_update_dpp(                                    \
        (int)0xFF800000, __float_as_int(bv), (CTRL), 0xf, 0xf, false);        \
    int oib = __builtin_amdgcn_update_dpp(                                    \
        0x7fffffff, bi, (CTRL), 0xf, 0xf, false);                             \
    float ov = __int_as_float(ovb);                                           \
    if (ov > bv || (ov == bv && oib < bi)) { bv = ov; bi = oib; }             \
  }

// Packed u32 max + runner-up over a 16-lane DPP row. m1 = max key,
// m2 = runner-up key of the union. key 0 = invalid sentinel.
#define KRED(CTRL)                                                            \
  {                                                                           \
    unsigned o1 = (unsigned)__builtin_amdgcn_update_dpp(                      \
        0, (int)m1, (CTRL), 0xf, 0xf, false);                                 \
    unsigned o2 = (unsigned)__builtin_amdgcn_update_dpp(                      \
        0, (int)m2, (CTRL), 0xf, 0xf, false);                                 \
    unsigned mn = min(m1, o1);                                                \
    m1 = max(m1, o1);                                                         \
    m2 = max(max(m2, o2), mn);                                                \
  }

struct Pick { int take; int nxt; };

// Tier-3: R5-verbatim exact full-row scan. Cold; kept out of the hot loop's
// instruction stream.
__device__ __noinline__ Pick tier3_scan(const float* __restrict__ GT,
                                        const float2* sdu, int row, int lane,
                                        float load, float lr, int depot) {
  const float NEGINF = -__builtin_inff();
  const float4* rowp = (const float4*)(GT + (size_t)row * NN);
  const float4* du4 = (const float4*)sdu;
  float fv = NEGINF;
  int fi = NN;
#pragma unroll
  for (int r = 0; r < 8; ++r) {
    float4 g4 = rowp[r * 64 + lane];
    float4 pA = du4[(r * 64 + lane) * 2];      // d0,u0,d1,u1
    float4 pB = du4[(r * 64 + lane) * 2 + 1];  // d2,u2,d3,u3
    float gl[4] = {g4.x, g4.y, g4.z, g4.w};
    float dl[4] = {pA.x, pA.z, pB.x, pB.z};
    float ul[4] = {pA.y, pA.w, pB.y, pB.w};
    float cv = NEGINF;
    int cj = 0;
#pragma unroll
    for (int j = 0; j < 4; ++j) {
      float tt = fmaf(ul[j], lr, gl[j]);
      bool feas = (dl[j] <= load);
      if (feas && tt > cv) { cv = tt; cj = j; }
    }
    if (cv > fv) { fv = cv; fi = 4 * (r * 64 + lane) + cj; }  // asc r: first-max
  }
  float bv = fv;
  int bi = fi;
  DPP_MERGE2(0x111); DPP_MERGE2(0x112); DPP_MERGE2(0x114);
  DPP_MERGE2(0x118); DPP_MERGE2(0x142); DPP_MERGE2(0x143);
  float fbv = __int_as_float(__builtin_amdgcn_readlane(__float_as_int(bv), 63));
  int fbi = __builtin_amdgcn_readlane(bi, 63);
  Pick p;
  p.take = (fbv > NEGINF) ? 1 : 0;
  p.nxt = p.take ? fbi : depot;
  return p;
}

// ---------------- sequential decode: ONE wave (R13-verbatim) ---------------------
__global__ __launch_bounds__(64, 1) void decode(const float* __restrict__ GT,
                                                const uint2* __restrict__ cand,
                                                const unsigned* __restrict__ pc16,
                                                const uint2* __restrict__ thrpk2,
                                                const float* __restrict__ u,
                                                const float* __restrict__ demands,
                                                const int* __restrict__ capp,
                                                const int* __restrict__ depotp,
                                                float* __restrict__ lrbuf,
                                                float* __restrict__ out) {
  __shared__ __align__(16) unsigned s_pc[NN * KL + 64];   // 123.1 KB packed lists
  __shared__ __align__(16) float2 s_du[NN];               // 16 KB (.x=d|+inf, .y=u)
  __shared__ __align__(16) uint2 s_thr[NN];               // 16 KB packed thresholds
  __shared__ __align__(16) unsigned short s_tour[TSTEPS + 2];  // 4.6 KB

  const int lane = threadIdx.x;
  const int depot = *depotp;
  const float capf = (float)(*capp);
  const float INF = __builtin_inff();
  const float C0 = 0.015625f;   // ALPHA / sqrt(HID), exact power of two
  const float MARGIN = 0.5f;    // >> any fp32 rounding in the bounds
  const float EGM = 0.0625f;    // > pack err 0.0156 + t-key trunc 0.0156 + rounding
  float* sduf = (float*)s_du;

  for (int i = lane; i < NN; i += 64) {
    s_du[i] = make_float2(demands[i], u[i]);
    s_thr[i] = thrpk2[i];
  }
  {
    const uint4* p4 = (const uint4*)pc16;
    uint4* q4 = (uint4*)s_pc;
    for (int i = lane; i < NN * KL / 4; i += 64) q4[i] = p4[i];
  }
  if (lane == 0) {
    sduf[2 * depot] = INF;  // depot starts visited
    s_tour[0] = (unsigned short)depot;
  }
  // single wave: per-wave LDS ordering suffices; no barrier needed

  int ntaken = 0, lasts = depot;
  float load = capf;
  float lr = load / capf;  // same fp32 division as reference
  int step = 0;
  const int lcl = (lane < KL) ? lane : (KL - 1);  // lanes >=15 duplicate entry 14

  for (; step < TSTEPS; ++step) {
    const int row = lasts;
    // ---- tier-1: 15 packed candidates, lanes 0-14 (pure LDS + VALU)
    unsigned pw = s_pc[row * KL + lcl];
    uint2 pk2 = s_thr[row];
    int i1x = (int)(pw & 0x7FFu);
    float2 du1 = s_du[i1x];              // dependent gather (ds_read_b64)
    float g1 = key2f(pw & 0xFFFFF800u);  // ghat <= g <= ghat + 0.0156
    float t1 = fmaf(du1.y, lr, g1);
    bool act = (lane < KL) && (du1.x <= load);
    unsigned m1 = act ? ((f2key(t1) & 0xFFFFF800u) | ((~(unsigned)i1x) & 0x7FFu)) : 0u;
    unsigned m2 = 0u;
    KRED(0x111); KRED(0x112); KRED(0x114); KRED(0x118);
    unsigned rv1k = (unsigned)__builtin_amdgcn_readlane((int)m1, 15);
    unsigned rv2k = (unsigned)__builtin_amdgcn_readlane((int)m2, 15);
    float rv1f = key2f(rv1k & 0xFFFFF800u);  // round-down: lower bd of winner t
    float rv2f = key2f(rv2k | 0x7FFu);       // round-up: upper bd of runner-up
    float t15 = __uint_as_float(pk2.x & 0xFFFF0000u);
    float m15 = __uint_as_float(pk2.x << 16);
    float B1 = fmaf(1.0f - lr, t15, lr * m15) + MARGIN;  // convex outside bound
    int take, nxt;
    if (__builtin_expect((rv1f > B1) && (rv1f > rv2f + EGM), 1)) {
      // certified: true t_w >= rv1f; rv1f > rv2f+EGM beats every other
      // in-list true t (trunc+pack err < EGM); rv1f > B1 beats every outside
      // node at this lr. Unique argmax == ref's pick. (No feasible cand ->
      // rv1k==0 -> rv1f NaN -> both compares false -> fallback.)
      take = 1;
      nxt = (int)((~rv1k) & 0x7FFu);
    } else {
      // ---- tier-2: on-demand exact eval of the 128-candidate list
      uint4 cc = ((const uint4*)(cand + (size_t)row * KCAND))[lane];
      float bv = -INF;
      int bi = 0x7fffffff;
      {
        float ga = __uint_as_float(cc.x); int ia = (int)cc.y;
        float gb = __uint_as_float(cc.z); int ib = (int)cc.w;
        float2 da = s_du[ia];
        float2 db = s_du[ib];
        float ta = fmaf(da.y, lr, ga);
        float tb = fmaf(db.y, lr, gb);
        if ((da.x <= load) && (ta > bv || (ta == bv && ia < bi))) { bv = ta; bi = ia; }
        if ((db.x <= load) && (tb > bv || (tb == bv && ib < bi))) { bv = tb; bi = ib; }
      }
      DPP_MERGE2(0x111); DPP_MERGE2(0x112); DPP_MERGE2(0x114);
      DPP_MERGE2(0x118); DPP_MERGE2(0x142); DPP_MERGE2(0x143);
      float rbv = __int_as_float(__builtin_amdgcn_readlane(__float_as_int(bv), 63));
      int rbi = __builtin_amdgcn_readlane(bi, 63);
      float t128 = __uint_as_float(pk2.y & 0xFFFF0000u);
      float m128 = __uint_as_float(pk2.y << 16);
      float B2 = fmaf(1.0f - lr, t128, lr * m128) + MARGIN;
      if (rbv > B2) {
        take = 1; nxt = rbi;
      } else {
        Pick p = tier3_scan(GT, (const float2*)s_du, row, lane, load, lr, depot);
        take = p.take; nxt = p.nxt;
      }
    }

    // ---- state update + output stores (identical fp ops to ref)
    if (lane == 0) {
      s_tour[1 + step] = (unsigned short)nxt;
      lrbuf[step] = take ? lr : -1.0f;  // fire-and-forget global store
    }
    if (take) {
      float dwin = s_du[nxt].x;  // raw demand (read BEFORE the INF mark below)
      load = load - dwin;        // same fp op sequence as reference
      ntaken++;
      if (lane == 0) sduf[2 * nxt] = INF;
    } else {
      load = capf;
      if (ntaken == NN - 1) { ++step; break; }  // done: ref emits (depot,0) on
    }
    lasts = nxt;
    lr = load / capf;  // same fp32 division as reference
  }

  // ref emits (depot, 0) forever once done
  for (int q = step + lane; q < TSTEPS; q += 64) {
    s_tour[1 + q] = (unsigned short)depot;
    lrbuf[q] = -1.0f;
  }
  // drain all outstanding global stores (lrbuf) before reading them back
  asm volatile("s_waitcnt vmcnt(0)" ::: "memory");
  // ---- flush tour; compute scores exactly in a parallel deferred pass
  for (int i = lane; i <= TSTEPS; i += 64) out[i] = (float)s_tour[i];
  for (int s = lane; s < TSTEPS; s += 64) {
    float lrs = lrbuf[s];
    float sc = 0.0f;
    if (lrs >= 0.0f) {
      int lastI = (int)s_tour[s];
      int biI = (int)s_tour[s + 1];
      float g = GT[(size_t)lastI * NN + biI];
      sc = fmaf(s_du[biI].y, lrs, g) * C0;  // identical expression to R3-R17
    }
    out[1 + TSTEPS + s] = sc;
  }
}

extern "C" void kernel_launch(void* const* d_in, const int* in_sizes, int n_in,
                              void* d_out, int out_size, void* d_ws, size_t ws_size,
                              hipStream_t stream) {
  const float* emb     = (const float*)d_in[0];  // [N, H]
  const float* demands = (const float*)d_in[1];  // [N]
  const float* Wq      = (const float*)d_in[2];  // [H, H+2]
  const float* bq      = (const float*)d_in[3];  // [H]
  const float* Wk      = (const float*)d_in[4];  // [H, H]
  const float* bk      = (const float*)d_in[5];  // [H]
  const int* cap       = (const int*)d_in[6];
  const int* depot     = (const int*)d_in[7];
  float* out           = (float*)d_out;          // 2305 tour + 2304 scores, fp32

  char* ws = (char*)d_ws;
  float* Kmat = (float*)(ws);                         // 8 MB  [N,H]
  float* Z    = (float*)(ws + ((size_t)8 << 20));     // 8 MB  [N,H]
  float* GT   = (float*)(ws + ((size_t)16 << 20));    // 16 MB [N,N] row=last, +v
  float* Wqh  = (float*)(ws + ((size_t)32 << 20));    // 4 MB  [H,H]; later overlaid
  float* u    = (float*)(ws + ((size_t)36 << 20));    // 8 KB
  float* v    = (float*)(ws + ((size_t)36 << 20) + 8192);
  float* sink = (float*)(ws + ((size_t)36 << 20) + 32768);  // warm sink (unused)
  // overlays of the dead Wqh region (Wqh dead after the Z GEMM):
  uint2* cnd  = (uint2*)Wqh;                                        // 2 MB
  unsigned* pc16g = (unsigned*)(ws + ((size_t)34 << 20));           // 120 KB
  uint2* thrpk2g  = (uint2*)(ws + ((size_t)34 << 20) + (128 << 10)); // 16 KB
  float* lrbuf    = (float*)(ws + ((size_t)34 << 20) + (160 << 10)); // 9.2 KB

  hipLaunchKernelGGL(prep_wqh, dim3(4096), dim3(256), 0, stream, Wq, Wqh);
  // K = emb @ Wk^T + bk  AND  Z = emb @ Wqh^T -- fused full-GPU dispatch
  hipLaunchKernelGGL(gemm_kz, dim3(HH / GT2, NN / GT2, 2), dim3(256), 0, stream,
                     emb, Wk, Wqh, bk, Kmat, Z);
  // u_i = K_i . Wq[:,H], v_i = K_i . bq
  hipLaunchKernelGGL(uv_k, dim3(NN), dim3(64), 0, stream, Kmat, Wq, bq, u, v);
  // GT = Z @ K^T + v (v==0 since bq==0 -> bit-identical)
  hipLaunchKernelGGL(gemm_nt128, dim3(NN / GT2, NN / GT2), dim3(256), 0, stream,
                     Z, HH, Kmat, HH, GT, NN, HH, v);
  // top-128 lists + packed top-15 + convex-bound thresholds (overlay dead Wqh)
  hipLaunchKernelGGL(prep_cand, dim3(NN), dim3(256), 0, stream, GT, u, cnd,
                     pc16g, thrpk2g);
  // pre-warm LLC with cand (2 MB) + pc16/thr for the on-demand fallbacks
  hipLaunchKernelGGL(warm_k, dim3(128), dim3(256), 0, stream,
                     (const float*)cnd, NN * KCAND * 2 + (160 << 8), sink);
  hipLaunchKernelGGL(decode, dim3(1), dim3(64), 0, stream, GT, cnd,
                     pc16g, thrpk2g, u, demands, cap, depot, lrbuf, out);
}

// Round 10
// 1811.761 us; speedup vs baseline: 1.2311x; 1.0165x over previous
//
#include <hip/hip_runtime.h>
#include <hip/hip_bf16.h>

// BeamDecoder: greedy CVRP-style decode.
// s_i(step) = c*( G[last,i] + (load/cap)*u_i )   (v==0 since bq==0; folded)
//
// R19: R18 confirmed decode floor (1310us, 3rd run) but total flat (1841
// vs 1837): prep "rest" swings +-100-200us across rounds with identical
// code -> noise-dominated; GEMM deltas invisible. One STRUCTURAL prep cost
// remains: prep_cand's serial bin-scan (thread 0 walks <=256 dependent LDS
// reads per radix pass; ~44K serial cyc/block x 2048 blocks). Replaced with
// a parallel 256-thread suffix-scan + atomicMax select, semantics identical
// to the serial loop (d* = max{d>=1 : S[d] >= need} else 0; s_need = need -
// S[d*+1], S[256]=0 -- matches break and no-break paths exactly; selection
// affects only WHICH equal-keyed duplicates fill the list, and soundness
// never depends on that: B-tests use the exact thresholds).
// Decode: only the s_pc prologue copy gets 4-batched loads for MLP; the
// step loop is R13-byte-identical. GEMMs = R18 (128^2/8x8, fused K+Z).
// If this round is flat too: decode is at its serial-dependency floor
// (2304 dependent steps x ~550cyc chain; R12/R14/R16/R17 structural
// attacks all regressed) and prep is GEMM-FLOP + noise bound -> declare.

#define NN 2048
#define HH 1024
#define TSTEPS (NN + NN / 8)   // 2304
#define GT2 128                // GEMM tile
#define KT 16
#define KCAND 128
#define KL 15

// ---------------- pack Wq[:, :H] into ld=1024 buffer ----------------
__global__ __launch_bounds__(256) void prep_wqh(const float* __restrict__ Wq,
                                                float* __restrict__ Wqh) {
  int id = blockIdx.x * 256 + threadIdx.x;
  int r = id >> 10, c = id & 1023;
  Wqh[id] = Wq[r * (HH + 2) + c];
}

// ---------------- NT GEMM body: C[128,128] tile = A[M,K] @ B[N,K]^T (+bias) ------
// Each output element's accumulation is a single FMA chain over ascending k
// -- bit-identical arithmetic to the original 64^2 kernel per element.
__device__ __forceinline__ void gemm_body(const float* __restrict__ A, int lda,
                                          const float* __restrict__ B, int ldb,
                                          float* __restrict__ C, int ldc,
                                          int K, const float* __restrict__ bias,
                                          int i0, int j0) {
  __shared__ float As[KT][GT2 + 4];
  __shared__ float Bs[KT][GT2 + 4];
  const int t = threadIdx.x;
  const int srow = t >> 2, sq = t & 3;
  const int tx = t & 15, ty = t >> 4;
  float acc[8][8] = {};
  for (int k0 = 0; k0 < K; k0 += KT) {
    float4 a0 = *(const float4*)&A[(size_t)(i0 + srow) * lda + k0 + sq * 4];
    float4 a1 = *(const float4*)&A[(size_t)(i0 + 64 + srow) * lda + k0 + sq * 4];
    float4 b0 = *(const float4*)&B[(size_t)(j0 + srow) * ldb + k0 + sq * 4];
    float4 b1 = *(const float4*)&B[(size_t)(j0 + 64 + srow) * ldb + k0 + sq * 4];
    __syncthreads();
    As[sq * 4 + 0][srow] = a0.x; As[sq * 4 + 1][srow] = a0.y;
    As[sq * 4 + 2][srow] = a0.z; As[sq * 4 + 3][srow] = a0.w;
    As[sq * 4 + 0][64 + srow] = a1.x; As[sq * 4 + 1][64 + srow] = a1.y;
    As[sq * 4 + 2][64 + srow] = a1.z; As[sq * 4 + 3][64 + srow] = a1.w;
    Bs[sq * 4 + 0][srow] = b0.x; Bs[sq * 4 + 1][srow] = b0.y;
    Bs[sq * 4 + 2][srow] = b0.z; Bs[sq * 4 + 3][srow] = b0.w;
    Bs[sq * 4 + 0][64 + srow] = b1.x; Bs[sq * 4 + 1][64 + srow] = b1.y;
    Bs[sq * 4 + 2][64 + srow] = b1.z; Bs[sq * 4 + 3][64 + srow] = b1.w;
    __syncthreads();
#pragma unroll
    for (int k = 0; k < KT; ++k) {
      float4 x0 = *(const float4*)&As[k][ty * 8];
      float4 x1 = *(const float4*)&As[k][ty * 8 + 4];
      float4 y0 = *(const float4*)&Bs[k][tx * 8];
      float4 y1 = *(const float4*)&Bs[k][tx * 8 + 4];
      float a[8] = {x0.x, x0.y, x0.z, x0.w, x1.x, x1.y, x1.z, x1.w};
      float b[8] = {y0.x, y0.y, y0.z, y0.w, y1.x, y1.y, y1.z, y1.w};
#pragma unroll
      for (int m = 0; m < 8; ++m)
#pragma unroll
        for (int n = 0; n < 8; ++n) acc[m][n] = fmaf(a[m], b[n], acc[m][n]);
    }
  }
  float bb[8] = {0.f, 0.f, 0.f, 0.f, 0.f, 0.f, 0.f, 0.f};
  if (bias) {
#pragma unroll
    for (int n = 0; n < 8; ++n) bb[n] = bias[j0 + tx * 8 + n];
  }
#pragma unroll
  for (int m = 0; m < 8; ++m) {
    float4 s0 = {acc[m][0] + bb[0], acc[m][1] + bb[1],
                 acc[m][2] + bb[2], acc[m][3] + bb[3]};
    float4 s1 = {acc[m][4] + bb[4], acc[m][5] + bb[5],
                 acc[m][6] + bb[6], acc[m][7] + bb[7]};
    *(float4*)&C[(size_t)(i0 + ty * 8 + m) * ldc + j0 + tx * 8] = s0;
    *(float4*)&C[(size_t)(i0 + ty * 8 + m) * ldc + j0 + tx * 8 + 4] = s1;
  }
}

// single GEMM (used for GT)
__global__ __launch_bounds__(256) void gemm_nt128(const float* __restrict__ A, int lda,
                                                  const float* __restrict__ B, int ldb,
                                                  float* __restrict__ C, int ldc,
                                                  int K, const float* __restrict__ bias) {
  gemm_body(A, lda, B, ldb, C, ldc, K, bias, blockIdx.y * GT2, blockIdx.x * GT2);
}

// fused K & Z GEMMs (independent; one full-GPU dispatch instead of two half)
__global__ __launch_bounds__(256) void gemm_kz(const float* __restrict__ emb,
                                               const float* __restrict__ Wk,
                                               const float* __restrict__ Wqh,
                                               const float* __restrict__ bk,
                                               float* __restrict__ Kmat,
                                               float* __restrict__ Z) {
  if (blockIdx.z == 0) {
    gemm_body(emb, HH, Wk, HH, Kmat, HH, HH, bk,
              blockIdx.y * GT2, blockIdx.x * GT2);
  } else {
    gemm_body(emb, HH, Wqh, HH, Z, HH, HH, (const float*)nullptr,
              blockIdx.y * GT2, blockIdx.x * GT2);
  }
}

// ---------------- u_i = K_i . Wq[:,H], v_i = K_i . bq  (one wave per row) ---------
__global__ __launch_bounds__(64) void uv_k(const float* __restrict__ Kmat,
                                           const float* __restrict__ Wq,
                                           const float* __restrict__ bq,
                                           float* __restrict__ u, float* __restrict__ v) {
  int i = blockIdx.x;
  int lane = threadIdx.x;
  float su = 0.f, sv = 0.f;
#pragma unroll
  for (int m = 0; m < HH / 64; ++m) {
    int j = lane + 64 * m;
    float kv = Kmat[(size_t)i * HH + j];
    su = fmaf(kv, Wq[(size_t)j * (HH + 2) + HH], su);
    sv = fmaf(kv, bq[j], sv);
  }
#pragma unroll
  for (int off = 32; off; off >>= 1) {
    su += __shfl_down(su, off, 64);
    sv += __shfl_down(sv, off, 64);
  }
  if (lane == 0) { u[i] = su; v[i] = sv; }
}

// ---------------- per-row exact top-K by g: 4-pass radix-select ----------------
__device__ __forceinline__ unsigned f2key(float f) {
  unsigned x = __float_as_uint(f);
  return x ^ ((x >> 31) ? 0xFFFFFFFFu : 0x80000000u);  // monotonic asc mapping
}
__device__ __forceinline__ float key2f(unsigned k) {
  unsigned x = (k & 0x80000000u) ? (k ^ 0x80000000u) : ~k;
  return __uint_as_float(x);
}
// bf16-style round-UP (toward +inf) of a float. ub16f(x) >= x always.
__device__ __forceinline__ unsigned ub16(float x) {
  unsigned b = __float_as_uint(x);
  if (x > 0.f && (b & 0xFFFFu)) b += 0x10000u;
  return b >> 16;
}

// Parallel bin-select: after the scatter phase, hist[] holds per-bin counts.
// Computes in place the suffix sum S[t] = sum_{e>=t} hist[e], then selects
// d* = max{d in [1,255] : S[d] >= need} (0 if none) and s_need = need -
// S[d*+1] (S[256]=0) -- exactly the serial walk's break/no-break semantics.
#define BIN_SELECT(need_)                                                     \
  {                                                                           \
    for (int off = 1; off < 256; off <<= 1) {                                 \
      int v = hist[t] + ((t + off < 256) ? hist[t + off] : 0);                \
      __syncthreads();                                                        \
      hist[t] = v;                                                            \
      __syncthreads();                                                        \
    }                                                                         \
    if (t == 0) s_d = 0;                                                      \
    __syncthreads();                                                          \
    if (t > 0 && hist[t] >= (need_)) atomicMax(&s_d, t);                      \
    __syncthreads();                                                          \
    if (t == 0) s_need = (need_) - ((s_d < 255) ? hist[s_d + 1] : 0);         \
    __syncthreads();                                                          \
  }

// Produces: cand[row][0..127] exact top-128 (value,idx); pc16[row][0..14]
// packed top-15 (key&~0x7FF | idx); thrpk2[row] = uint2:
//   .x = ub16(thr15)<<16 | ub16(M1_15)    (+inf halves when row flagged)
//   .y = ub16(thr128)<<16 | ub16(M1_128)
// where M1_K = max over j NOT in the stored top-K list of (g_j + u_j).
// Flag: any stored top-15 entry with |g|+|u| >= 128 (bounds both the 21-bit
// g-pack error and the decode-side t-key truncation error to <= 0.0156).
__global__ __launch_bounds__(256) void prep_cand(const float* __restrict__ GT,
                                                 const float* __restrict__ u,
                                                 uint2* __restrict__ cand,
                                                 unsigned* __restrict__ pc16,
                                                 uint2* __restrict__ thrpk2) {
  __shared__ float rowv[NN];
  __shared__ float su_[NN];
  __shared__ int hist[256];
  __shared__ float red15[256];
  __shared__ float red128[256];
  __shared__ unsigned c128k[KCAND];
  __shared__ int c128i[KCAND];
  __shared__ unsigned char markA[NN];  // in stored top-128
  __shared__ unsigned char markB[NN];  // in stored top-15
  __shared__ int s_d, s_need, s_gt, s_eq, s_gt2, s_eq2, s_flag;
  const int row = blockIdx.x, t = threadIdx.x;
  for (int i = t; i < NN; i += 256) {
    rowv[i] = GT[(size_t)row * NN + i];
    su_[i] = u[i];
    markA[i] = 0;
    markB[i] = 0;
  }
  __syncthreads();
  unsigned prefix = 0;
  int need = KCAND;
  for (int pass = 0; pass < 4; ++pass) {
    hist[t] = 0;
    __syncthreads();
    const int shift = 24 - 8 * pass;
    for (int i = t; i < NN; i += 256) {
      unsigned k = f2key(rowv[i]);
      if (pass == 0 || (k >> (shift + 8)) == (prefix >> (shift + 8)))
        atomicAdd(&hist[(k >> shift) & 0xFF], 1);
    }
    __syncthreads();
    BIN_SELECT(need);
    prefix |= ((unsigned)s_d) << shift;
    need = s_need;
    __syncthreads();
  }
  const unsigned thrk = prefix;  // exact KCAND-th largest key
  if (t == 0) { s_gt = 0; s_eq = 0; }
  __syncthreads();
  for (int i = t; i < NN; i += 256) {
    unsigned k = f2key(rowv[i]);
    if (k > thrk) {
      int p = atomicAdd(&s_gt, 1);
      cand[(size_t)row * KCAND + p] = make_uint2(__float_as_uint(rowv[i]), (unsigned)i);
      c128k[p] = k;
      c128i[p] = i;
      markA[i] = 1;
    }
  }
  __syncthreads();
  const int cgt = s_gt;
  for (int i = t; i < NN; i += 256) {
    if (f2key(rowv[i]) == thrk) {
      int p = atomicAdd(&s_eq, 1);
      if (p < KCAND - cgt) {
        cand[(size_t)row * KCAND + cgt + p] = make_uint2(__float_as_uint(rowv[i]), (unsigned)i);
        c128k[cgt + p] = thrk;
        c128i[cgt + p] = i;
        markA[i] = 1;
      }
    }
  }
  __syncthreads();
  // ---- exact 15th-largest among the 128 keys (== row's top-15 multiset)
  unsigned pfx2 = 0;
  need = KL;
  for (int pass = 0; pass < 4; ++pass) {
    hist[t] = 0;
    __syncthreads();
    const int shift = 24 - 8 * pass;
    for (int i = t; i < KCAND; i += 256) {
      unsigned k = c128k[i];
      if (pass == 0 || (k >> (shift + 8)) == (pfx2 >> (shift + 8)))
        atomicAdd(&hist[(k >> shift) & 0xFF], 1);
    }
    __syncthreads();
    BIN_SELECT(need);
    pfx2 |= ((unsigned)s_d) << shift;
    need = s_need;
    __syncthreads();
  }
  const unsigned thrk15 = pfx2;
  if (t == 0) { s_gt2 = 0; s_eq2 = 0; s_flag = 0; }
  __syncthreads();
  for (int i = t; i < KCAND; i += 256) {
    if (c128k[i] > thrk15) {
      int p = atomicAdd(&s_gt2, 1);
      pc16[(size_t)row * KL + p] = (c128k[i] & 0xFFFFF800u) | (unsigned)c128i[i];
      markB[c128i[i]] = 1;
      if (fabsf(key2f(c128k[i])) + fabsf(su_[c128i[i]]) >= 128.0f) s_flag = 1;
    }
  }
  __syncthreads();
  const int cgt2 = s_gt2;
  for (int i = t; i < KCAND; i += 256) {
    if (c128k[i] == thrk15) {
      int p = atomicAdd(&s_eq2, 1);
      if (p < KL - cgt2) {
        pc16[(size_t)row * KL + cgt2 + p] = (thrk15 & 0xFFFFF800u) | (unsigned)c128i[i];
        markB[c128i[i]] = 1;
        if (fabsf(key2f(thrk15)) + fabsf(su_[c128i[i]]) >= 128.0f) s_flag = 1;
      }
    }
  }
  if (t == 0 && fabsf(key2f(thrk15)) >= 128.0f) s_flag = 1;
  __syncthreads();
  // ---- M1_15 / M1_128: max of (g + u) over nodes outside each stored list
  float lm15 = -__builtin_inff(), lm128 = -__builtin_inff();
  for (int i = t; i < NN; i += 256) {
    float gu = rowv[i] + su_[i];
    if (!markB[i]) lm15 = fmaxf(lm15, gu);
    if (!markA[i]) lm128 = fmaxf(lm128, gu);
  }
  red15[t] = lm15;
  red128[t] = lm128;
  __syncthreads();
  for (int s = 128; s; s >>= 1) {
    if (t < s) {
      red15[t] = fmaxf(red15[t], red15[t + s]);
      red128[t] = fmaxf(red128[t], red128[t + s]);
    }
    __syncthreads();
  }
  if (t == 0) {
    const float INF = __builtin_inff();
    float t15 = s_flag ? INF : key2f(thrk15);
    float m15 = s_flag ? INF : red15[0];
    thrpk2[row] = make_uint2((ub16(t15) << 16) | ub16(m15),
                             (ub16(key2f(thrk)) << 16) | ub16(red128[0]));
  }
}

// ---------------- LLC pre-warm for the tier-2 fallback lists ---------------------
__global__ __launch_bounds__(256) void warm_k(const float* __restrict__ a, int n,
                                              float* __restrict__ sink) {
  float s = 0.f;
  const float4* a4 = (const float4*)a;
  for (int i = threadIdx.x; i < n / 4; i += 256) {
    float4 x = a4[i];
    s += x.x + x.y + x.z + x.w;
  }
  if (s == 1.2345e-30f) sink[blockIdx.x] = s;  // never true; keeps loads alive
}

// DPP merge of (bv,bi): max value, smallest index on ties. Invalid lanes get
// (-inf, INT_MAX).
#define DPP_MERGE2(CTRL)                                                      \
  {                                                                           \
    int ovb = __builtin_amdgcn_update_dpp(                                    \
        (int)0xFF800000, __float_as_int(bv), (CTRL), 0xf, 0xf, false);        \
    int oib = __builtin_amdgcn_update_dpp(                                    \
        0x7fffffff, bi, (CTRL), 0xf, 0xf, false);                             \
    float ov = __int_as_float(ovb);                                           \
    if (ov > bv || (ov == bv && oib < bi)) { bv = ov; bi = oib; }             \
  }

// Packed u32 max + runner-up over a 16-lane DPP row. m1 = max key,
// m2 = runner-up key of the union. key 0 = invalid sentinel.
#define KRED(CTRL)                                                            \
  {                                                                           \
    unsigned o1 = (unsigned)__builtin_amdgcn_update_dpp(                      \
        0, (int)m1, (CTRL), 0xf, 0xf, false);                                 \
    unsigned o2 = (unsigned)__builtin_amdgcn_update_dpp(                      \
        0, (int)m2, (CTRL), 0xf, 0xf, false);                                 \
    unsigned mn = min(m1, o1);                                                \
    m1 = max(m1, o1);                                                         \
    m2 = max(max(m2, o2), mn);                                                \
  }

struct Pick { int take; int nxt; };

// Tier-3: R5-verbatim exact full-row scan. Cold; kept out of the hot loop's
// instruction stream.
__device__ __noinline__ Pick tier3_scan(const float* __restrict__ GT,
                                        const float2* sdu, int row, int lane,
                                        float load, float lr, int depot) {
  const float NEGINF = -__builtin_inff();
  const float4* rowp = (const float4*)(GT + (size_t)row * NN);
  const float4* du4 = (const float4*)sdu;
  float fv = NEGINF;
  int fi = NN;
#pragma unroll
  for (int r = 0; r < 8; ++r) {
    float4 g4 = rowp[r * 64 + lane];
    float4 pA = du4[(r * 64 + lane) * 2];      // d0,u0,d1,u1
    float4 pB = du4[(r * 64 + lane) * 2 + 1];  // d2,u2,d3,u3
    float gl[4] = {g4.x, g4.y, g4.z, g4.w};
    float dl[4] = {pA.x, pA.z, pB.x, pB.z};
    float ul[4] = {pA.y, pA.w, pB.y, pB.w};
    float cv = NEGINF;
    int cj = 0;
#pragma unroll
    for (int j = 0; j < 4; ++j) {
      float tt = fmaf(ul[j], lr, gl[j]);
      bool feas = (dl[j] <= load);
      if (feas && tt > cv) { cv = tt; cj = j; }
    }
    if (cv > fv) { fv = cv; fi = 4 * (r * 64 + lane) + cj; }  // asc r: first-max
  }
  float bv = fv;
  int bi = fi;
  DPP_MERGE2(0x111); DPP_MERGE2(0x112); DPP_MERGE2(0x114);
  DPP_MERGE2(0x118); DPP_MERGE2(0x142); DPP_MERGE2(0x143);
  float fbv = __int_as_float(__builtin_amdgcn_readlane(__float_as_int(bv), 63));
  int fbi = __builtin_amdgcn_readlane(bi, 63);
  Pick p;
  p.take = (fbv > NEGINF) ? 1 : 0;
  p.nxt = p.take ? fbi : depot;
  return p;
}

// ---------------- sequential decode: ONE wave (R13-verbatim step loop) -----------
__global__ __launch_bounds__(64, 1) void decode(const float* __restrict__ GT,
                                                const uint2* __restrict__ cand,
                                                const unsigned* __restrict__ pc16,
                                                const uint2* __restrict__ thrpk2,
                                                const float* __restrict__ u,
                                                const float* __restrict__ demands,
                                                const int* __restrict__ capp,
                                                const int* __restrict__ depotp,
                                                float* __restrict__ lrbuf,
                                                float* __restrict__ out) {
  __shared__ __align__(16) unsigned s_pc[NN * KL + 64];   // 123.1 KB packed lists
  __shared__ __align__(16) float2 s_du[NN];               // 16 KB (.x=d|+inf, .y=u)
  __shared__ __align__(16) uint2 s_thr[NN];               // 16 KB packed thresholds
  __shared__ __align__(16) unsigned short s_tour[TSTEPS + 2];  // 4.6 KB

  const int lane = threadIdx.x;
  const int depot = *depotp;
  const float capf = (float)(*capp);
  const float INF = __builtin_inff();
  const float C0 = 0.015625f;   // ALPHA / sqrt(HID), exact power of two
  const float MARGIN = 0.5f;    // >> any fp32 rounding in the bounds
  const float EGM = 0.0625f;    // > pack err 0.0156 + t-key trunc 0.0156 + rounding
  float* sduf = (float*)s_du;

  for (int i = lane; i < NN; i += 64) {
    s_du[i] = make_float2(demands[i], u[i]);
    s_thr[i] = thrpk2[i];
  }
  {
    // 4-batched copy: 4 independent global loads in flight per iteration
    const uint4* p4 = (const uint4*)pc16;
    uint4* q4 = (uint4*)s_pc;
    for (int i = lane; i < NN * KL / 4; i += 256) {  // 7680 total, 30 iters
      uint4 a = p4[i];
      uint4 b = p4[i + 64];
      uint4 c = p4[i + 128];
      uint4 d = p4[i + 192];
      q4[i] = a; q4[i + 64] = b; q4[i + 128] = c; q4[i + 192] = d;
    }
  }
  if (lane == 0) {
    sduf[2 * depot] = INF;  // depot starts visited
    s_tour[0] = (unsigned short)depot;
  }
  // single wave: per-wave LDS ordering suffices; no barrier needed

  int ntaken = 0, lasts = depot;
  float load = capf;
  float lr = load / capf;  // same fp32 division as reference
  int step = 0;
  const int lcl = (lane < KL) ? lane : (KL - 1);  // lanes >=15 duplicate entry 14

  for (; step < TSTEPS; ++step) {
    const int row = lasts;
    // ---- tier-1: 15 packed candidates, lanes 0-14 (pure LDS + VALU)
    unsigned pw = s_pc[row * KL + lcl];
    uint2 pk2 = s_thr[row];
    int i1x = (int)(pw & 0x7FFu);
    float2 du1 = s_du[i1x];              // dependent gather (ds_read_b64)
    float g1 = key2f(pw & 0xFFFFF800u);  // ghat <= g <= ghat + 0.0156
    float t1 = fmaf(du1.y, lr, g1);
    bool act = (lane < KL) && (du1.x <= load);
    unsigned m1 = act ? ((f2key(t1) & 0xFFFFF800u) | ((~(unsigned)i1x) & 0x7FFu)) : 0u;
    unsigned m2 = 0u;
    KRED(0x111); KRED(0x112); KRED(0x114); KRED(0x118);
    unsigned rv1k = (unsigned)__builtin_amdgcn_readlane((int)m1, 15);
    unsigned rv2k = (unsigned)__builtin_amdgcn_readlane((int)m2, 15);
    float rv1f = key2f(rv1k & 0xFFFFF800u);  // round-down: lower bd of winner t
    float rv2f = key2f(rv2k | 0x7FFu);       // round-up: upper bd of runner-up
    float t15 = __uint_as_float(pk2.x & 0xFFFF0000u);
    float m15 = __uint_as_float(pk2.x << 16);
    float B1 = fmaf(1.0f - lr, t15, lr * m15) + MARGIN;  // convex outside bound
    int take, nxt;
    if (__builtin_expect((rv1f > B1) && (rv1f > rv2f + EGM), 1)) {
      // certified: true t_w >= rv1f; rv1f > rv2f+EGM beats every other
      // in-list true t (trunc+pack err < EGM); rv1f > B1 beats every outside
      // node at this lr. Unique argmax == ref's pick. (No feasible cand ->
      // rv1k==0 -> rv1f NaN -> both compares false -> fallback.)
      take = 1;
      nxt = (int)((~rv1k) & 0x7FFu);
    } else {
      // ---- tier-2: on-demand exact eval of the 128-candidate list
      uint4 cc = ((const uint4*)(cand + (size_t)row * KCAND))[lane];
      float bv = -INF;
      int bi = 0x7fffffff;
      {
        float ga = __uint_as_float(cc.x); int ia = (int)cc.y;
        float gb = __uint_as_float(cc.z); int ib = (int)cc.w;
        float2 da = s_du[ia];
        float2 db = s_du[ib];
        float ta = fmaf(da.y, lr, ga);
        float tb = fmaf(db.y, lr, gb);
        if ((da.x <= load) && (ta > bv || (ta == bv && ia < bi))) { bv = ta; bi = ia; }
        if ((db.x <= load) && (tb > bv || (tb == bv && ib < bi))) { bv = tb; bi = ib; }
      }
      DPP_MERGE2(0x111); DPP_MERGE2(0x112); DPP_MERGE2(0x114);
      DPP_MERGE2(0x118); DPP_MERGE2(0x142); DPP_MERGE2(0x143);
      float rbv = __int_as_float(__builtin_amdgcn_readlane(__float_as_int(bv), 63));
      int rbi = __builtin_amdgcn_readlane(bi, 63);
      float t128 = __uint_as_float(pk2.y & 0xFFFF0000u);
      float m128 = __uint_as_float(pk2.y << 16);
      float B2 = fmaf(1.0f - lr, t128, lr * m128) + MARGIN;
      if (rbv > B2) {
        take = 1; nxt = rbi;
      } else {
        Pick p = tier3_scan(GT, (const float2*)s_du, row, lane, load, lr, depot);
        take = p.take; nxt = p.nxt;
      }
    }

    // ---- state update + output stores (identical fp ops to ref)
    if (lane == 0) {
      s_tour[1 + step] = (unsigned short)nxt;
      lrbuf[step] = take ? lr : -1.0f;  // fire-and-forget global store
    }
    if (take) {
      float dwin = s_du[nxt].x;  // raw demand (read BEFORE the INF mark below)
      load = load - dwin;        // same fp op sequence as reference
      ntaken++;
      if (lane == 0) sduf[2 * nxt] = INF;
    } else {
      load = capf;
      if (ntaken == NN - 1) { ++step; break; }  // done: ref emits (depot,0) on
    }
    lasts = nxt;
    lr = load / capf;  // same fp32 division as reference
  }

  // ref emits (depot, 0) forever once done
  for (int q = step + lane; q < TSTEPS; q += 64) {
    s_tour[1 + q] = (unsigned short)depot;
    lrbuf[q] = -1.0f;
  }
  // drain all outstanding global stores (lrbuf) before reading them back
  asm volatile("s_waitcnt vmcnt(0)" ::: "memory");
  // ---- flush tour; compute scores exactly in a parallel deferred pass
  for (int i = lane; i <= TSTEPS; i += 64) out[i] = (float)s_tour[i];
  for (int s = lane; s < TSTEPS; s += 64) {
    float lrs = lrbuf[s];
    float sc = 0.0f;
    if (lrs >= 0.0f) {
      int lastI = (int)s_tour[s];
      int biI = (int)s_tour[s + 1];
      float g = GT[(size_t)lastI * NN + biI];
      sc = fmaf(s_du[biI].y, lrs, g) * C0;  // identical expression to R3-R18
    }
    out[1 + TSTEPS + s] = sc;
  }
}

extern "C" void kernel_launch(void* const* d_in, const int* in_sizes, int n_in,
                              void* d_out, int out_size, void* d_ws, size_t ws_size,
                              hipStream_t stream) {
  const float* emb     = (const float*)d_in[0];  // [N, H]
  const float* demands = (const float*)d_in[1];  // [N]
  const float* Wq      = (const float*)d_in[2];  // [H, H+2]
  const float* bq      = (const float*)d_in[3];  // [H]
  const float* Wk      = (const float*)d_in[4];  // [H, H]
  const float* bk      = (const float*)d_in[5];  // [H]
  const int* cap       = (const int*)d_in[6];
  const int* depot     = (const int*)d_in[7];
  float* out           = (float*)d_out;          // 2305 tour + 2304 scores, fp32

  char* ws = (char*)d_ws;
  float* Kmat = (float*)(ws);                         // 8 MB  [N,H]
  float* Z    = (float*)(ws + ((size_t)8 << 20));     // 8 MB  [N,H]
  float* GT   = (float*)(ws + ((size_t)16 << 20));    // 16 MB [N,N] row=last, +v
  float* Wqh  = (float*)(ws + ((size_t)32 << 20));    // 4 MB  [H,H]; later overlaid
  float* u    = (float*)(ws + ((size_t)36 << 20));    // 8 KB
  float* v    = (float*)(ws + ((size_t)36 << 20) + 8192);
  float* sink = (float*)(ws + ((size_t)36 << 20) + 32768);  // warm sink (unused)
  // overlays of the dead Wqh region (Wqh dead after the Z GEMM):
  uint2* cnd  = (uint2*)Wqh;                                        // 2 MB
  unsigned* pc16g = (unsigned*)(ws + ((size_t)34 << 20));           // 120 KB
  uint2* thrpk2g  = (uint2*)(ws + ((size_t)34 << 20) + (128 << 10)); // 16 KB
  float* lrbuf    = (float*)(ws + ((size_t)34 << 20) + (160 << 10)); // 9.2 KB

  hipLaunchKernelGGL(prep_wqh, dim3(4096), dim3(256), 0, stream, Wq, Wqh);
  // K = emb @ Wk^T + bk  AND  Z = emb @ Wqh^T -- fused full-GPU dispatch
  hipLaunchKernelGGL(gemm_kz, dim3(HH / GT2, NN / GT2, 2), dim3(256), 0, stream,
                     emb, Wk, Wqh, bk, Kmat, Z);
  // u_i = K_i . Wq[:,H], v_i = K_i . bq
  hipLaunchKernelGGL(uv_k, dim3(NN), dim3(64), 0, stream, Kmat, Wq, bq, u, v);
  // GT = Z @ K^T + v (v==0 since bq==0 -> bit-identical)
  hipLaunchKernelGGL(gemm_nt128, dim3(NN / GT2, NN / GT2), dim3(256), 0, stream,
                     Z, HH, Kmat, HH, GT, NN, HH, v);
  // top-128 lists + packed top-15 + convex-bound thresholds (overlay dead Wqh)
  hipLaunchKernelGGL(prep_cand, dim3(NN), dim3(256), 0, stream, GT, u, cnd,
                     pc16g, thrpk2g);
  // pre-warm LLC with cand (2 MB) + pc16/thr for the on-demand fallbacks
  hipLaunchKernelGGL(warm_k, dim3(128), dim3(256), 0, stream,
                     (const float*)cnd, NN * KCAND * 2 + (160 << 8), sink);
  hipLaunchKernelGGL(decode, dim3(1), dim3(64), 0, stream, GT, cnd,
                     pc16g, thrpk2g, u, demands, cap, depot, lrbuf, out);
}